// Round 2
// baseline (1603.754 us; speedup 1.0000x reference)
//
#include <hip/hip_runtime.h>
#include <hip/hip_bf16.h>
#include <math.h>

#define DIMC 256
#define NB   4
#define HH   128
#define WW   128
#define HWs  16384
#define HID  256
#define C2   512
#define EPSf 1e-5f

typedef __hip_bfloat16 bf;

__device__ __forceinline__ float b2f(bf v){ return __bfloat162float(v); }
__device__ __forceinline__ bf    f2b(float v){ return __float2bfloat16(v); }

__device__ __forceinline__ float ldf(const float* p){ return *p; }
__device__ __forceinline__ float ldf(const bf* p){ return __bfloat162float(*p); }

__device__ __forceinline__ void unpack2(unsigned u, float& a, float& b){
  union{unsigned x; float f;} lo, hi;
  lo.x = u << 16; hi.x = u & 0xffff0000u;
  a = lo.f; b = hi.f;
}
__device__ __forceinline__ void load8(const float* p, float* v){
  float4 a = *(const float4*)p, b = *(const float4*)(p+4);
  v[0]=a.x;v[1]=a.y;v[2]=a.z;v[3]=a.w;v[4]=b.x;v[5]=b.y;v[6]=b.z;v[7]=b.w;
}
__device__ __forceinline__ void load8(const bf* p, float* v){
  uint4 u = *(const uint4*)p;
  unpack2(u.x,v[0],v[1]); unpack2(u.y,v[2],v[3]);
  unpack2(u.z,v[4],v[5]); unpack2(u.w,v[6],v[7]);
}
__device__ __forceinline__ void load4(const float* p, float* v){
  float4 a = *(const float4*)p; v[0]=a.x;v[1]=a.y;v[2]=a.z;v[3]=a.w;
}
__device__ __forceinline__ void load4(const bf* p, float* v){
  uint2 u = *(const uint2*)p;
  unpack2(u.x,v[0],v[1]); unpack2(u.y,v[2],v[3]);
}
struct alignas(8) bf4s { bf a,b,c,d; };
__device__ __forceinline__ void store4(float* p, const float* v){
  *(float4*)p = make_float4(v[0],v[1],v[2],v[3]);
}
__device__ __forceinline__ void store4(bf* p, const float* v){
  bf4s s; s.a=f2b(v[0]); s.b=f2b(v[1]); s.c=f2b(v[2]); s.d=f2b(v[3]);
  *(bf4s*)p = s;
}

__device__ __forceinline__ float gelu_exact(float v){
  return 0.5f*v*(1.0f + erff(v*0.70710678118654752f));
}

// ---------------- LayerNorm over channel dim (per pixel), bf16 out ----------------
template<typename TI>
__global__ __launch_bounds__(256) void ln_kernel(const TI* __restrict__ x,
    const float* __restrict__ w, const float* __restrict__ bb, bf* __restrict__ y){
  int p = blockIdx.x*256 + threadIdx.x;
  int b  = p >> 14;
  int sp = p & (HWs-1);
  const TI* xb = x + (size_t)b*DIMC*HWs + sp;
  float s = 0.f, s2 = 0.f;
  for(int c=0;c<DIMC;c++){ float v = ldf(xb + (size_t)c*HWs); s += v; s2 += v*v; }
  float mu   = s * (1.0f/DIMC);
  float var  = s2 * (1.0f/DIMC) - mu*mu;
  float rinv = rsqrtf(var + EPSf);
  bf* yb = y + (size_t)b*DIMC*HWs + sp;
  for(int c=0;c<DIMC;c++){
    float v = ldf(xb + (size_t)c*HWs);
    yb[(size_t)c*HWs] = f2b((v - mu)*rinv*w[c] + bb[c]);
  }
}

// ---------------- global average pool per (b,c) ----------------
__global__ __launch_bounds__(256) void gp_kernel(const bf* __restrict__ y, float* __restrict__ gp){
  int bc = blockIdx.x;
  const bf* pl = y + (size_t)bc*HWs;
  float s = 0.f;
  for(int i=threadIdx.x;i<HWs;i+=256) s += b2f(pl[i]);
  __shared__ float red[256];
  red[threadIdx.x] = s; __syncthreads();
  for(int o=128;o>0;o>>=1){
    if(threadIdx.x<o) red[threadIdx.x] += red[threadIdx.x+o];
    __syncthreads();
  }
  if(threadIdx.x==0) gp[bc] = red[0]*(1.0f/HWs);
}

// ---------------- gating MLP (tiny) ----------------
__global__ __launch_bounds__(256) void gate_kernel(const float* __restrict__ gp,
    const float* __restrict__ g1w, const float* __restrict__ g1b,
    const float* __restrict__ g2w, const float* __restrict__ g2b,
    float* __restrict__ cwaw){
  __shared__ float h[NB][64];
  __shared__ float zz[NB][2];
  int t = threadIdx.x;
  int b = t >> 6, j = t & 63;
  const float* gpb = gp + b*DIMC;
  const float* wr  = g1w + j*DIMC;
  float s = g1b[j];
  for(int c=0;c<DIMC;c++) s += gpb[c]*wr[c];
  h[b][j] = fmaxf(s, 0.f);
  __syncthreads();
  if (t < 8){
    int b2 = t >> 1, o = t & 1;
    float z = g2b[o];
    const float* w2 = g2w + o*64;
    for(int q=0;q<64;q++) z += w2[q]*h[b2][q];
    zz[b2][o] = z;
  }
  __syncthreads();
  if (t < 4){
    float z0 = zz[t][0], z1 = zz[t][1];
    float mm = fmaxf(z0,z1);
    float e0 = __expf(z0-mm), e1 = __expf(z1-mm);
    float inv = 1.0f/(e0+e1);
    cwaw[2*t]   = e0*inv;
    cwaw[2*t+1] = e1*inv;
  }
}

// ---------------- depthwise conv 3x3 + 5x5 + biases ----------------
__global__ __launch_bounds__(256) void dwconv_kernel(const bf* __restrict__ y,
    const float* __restrict__ w3, const float* __restrict__ b3,
    const float* __restrict__ w5, const float* __restrict__ b5,
    bf* __restrict__ out){
  int idx = blockIdx.x*256 + threadIdx.x;
  int wx = idx & 127;
  int rest = idx >> 7;
  int hy = rest & 127; rest >>= 7;
  int c  = rest & 255;
  int b  = rest >> 8;
  const bf* pl = y + ((size_t)b*DIMC + c)*HWs;
  const float* k3 = w3 + c*9;
  const float* k5 = w5 + c*25;
  float acc = b3[c] + b5[c];
  #pragma unroll
  for(int di=-2; di<=2; di++){
    int yy = hy + di;
    if((unsigned)yy >= (unsigned)HH) continue;
    const bf* prow = pl + yy*WW;
    #pragma unroll
    for(int dj=-2; dj<=2; dj++){
      int xx = wx + dj;
      if((unsigned)xx >= (unsigned)WW) continue;
      float v = b2f(prow[xx]);
      acc += v * k5[(di+2)*5 + (dj+2)];
      if (di>=-1 && di<=1 && dj>=-1 && dj<=1)
        acc += v * k3[(di+1)*3 + (dj+1)];
    }
  }
  out[idx] = f2b(acc);
}

// ---------------- grouped conv (2-in 2-out per group, 3x3) ----------------
__global__ __launch_bounds__(256) void dwconv2_kernel(const bf* __restrict__ p,
    const float* __restrict__ w, bf* __restrict__ out){
  int idx = blockIdx.x*256 + threadIdx.x;
  int wx = idx & 127;
  int rest = idx >> 7;
  int hy = rest & 127; rest >>= 7;
  int o  = rest & 511;
  int b  = rest >> 9;
  int g0 = (o >> 1) << 1;
  const bf* p0 = p + ((size_t)b*C2 + g0)*HWs;
  const bf* p1 = p0 + HWs;
  const float* k0 = w + o*18;
  const float* k1 = k0 + 9;
  float acc = 0.f;
  #pragma unroll
  for(int di=-1; di<=1; di++){
    int yy = hy + di;
    if((unsigned)yy >= (unsigned)HH) continue;
    const bf* r0 = p0 + yy*WW;
    const bf* r1 = p1 + yy*WW;
    #pragma unroll
    for(int dj=-1; dj<=1; dj++){
      int xx = wx + dj;
      if((unsigned)xx >= (unsigned)WW) continue;
      int ki = (di+1)*3 + (dj+1);
      acc += b2f(r0[xx])*k0[ki] + b2f(r1[xx])*k1[ki];
    }
  }
  out[idx] = f2b(acc);
}

// ---------------- fp32-math GEMM over bf16 acts: out[b,o,p] = sum_k A[o,k]*Bact[b,k,p] ----------------
// MODE 0: plain; MODE 1: mix (cw*act1+aw*act2) +bias +resid; MODE 2: glu (gelu(x1)*x2) +resid
template<int MODE, typename TRES, typename TOUT>
__global__ __launch_bounds__(256) void gemm_kernel(
    const float* __restrict__ A, const bf* __restrict__ act1,
    const bf* __restrict__ act2, const float* __restrict__ cwaw,
    const float* __restrict__ bias, const TRES* __restrict__ resid,
    TOUT* __restrict__ out, int K, int Cact, int Oc)
{
  __shared__ float As[16][132];
  __shared__ float Bs[16][132];
  int t  = threadIdx.x;
  int n0 = blockIdx.x * 128;
  int o0 = blockIdx.y * 128;
  int b  = n0 >> 14;
  int sp = n0 & (HWs-1);
  const bf* actb1 = act1 + (size_t)b*Cact*HWs + sp;
  const bf* actb2 = (MODE==1) ? act2 + (size_t)b*Cact*HWs + sp : nullptr;
  float cw = 0.f, aw = 0.f;
  if (MODE==1){ cw = cwaw[2*b]; aw = cwaw[2*b+1]; }
  int tx = t & 15, ty = t >> 4;
  float acc[8][8];
  #pragma unroll
  for(int i=0;i<8;i++)
    #pragma unroll
    for(int j=0;j<8;j++) acc[i][j]=0.f;
  int am = t & 127;
  int ak = (t >> 7) << 3;
  int bk = t >> 4;
  int bn = (t & 15) << 3;

  for(int k0=0;k0<K;k0+=16){
    const float* Ap = A + (size_t)(o0+am)*K + (k0+ak);
    float av[8]; load8(Ap, av);
    #pragma unroll
    for(int q=0;q<8;q++) As[ak+q][am]=av[q];

    float bv[8];
    const bf* B1 = actb1 + (size_t)(k0+bk)*HWs + bn;
    if (MODE==0){
      load8(B1, bv);
    } else if (MODE==1){
      float u[8], v[8];
      load8(B1, u);
      load8(actb2 + (size_t)(k0+bk)*HWs + bn, v);
      #pragma unroll
      for(int q=0;q<8;q++) bv[q] = cw*u[q] + aw*v[q];
    } else {
      float u[8], v[8];
      load8(B1, u);
      load8(B1 + (size_t)HID*HWs, v);
      #pragma unroll
      for(int q=0;q<8;q++) bv[q] = gelu_exact(u[q])*v[q];
    }
    *(float4*)&Bs[bk][bn]   = make_float4(bv[0],bv[1],bv[2],bv[3]);
    *(float4*)&Bs[bk][bn+4] = make_float4(bv[4],bv[5],bv[6],bv[7]);
    __syncthreads();
    #pragma unroll
    for(int kk=0;kk<16;kk++){
      float4 t0 = *(const float4*)&As[kk][ty*4];
      float4 t1 = *(const float4*)&As[kk][ty*4+64];
      float4 t2 = *(const float4*)&Bs[kk][tx*4];
      float4 t3 = *(const float4*)&Bs[kk][tx*4+64];
      float ra[8] = {t0.x,t0.y,t0.z,t0.w,t1.x,t1.y,t1.z,t1.w};
      float rb[8] = {t2.x,t2.y,t2.z,t2.w,t3.x,t3.y,t3.z,t3.w};
      #pragma unroll
      for(int i=0;i<8;i++)
        #pragma unroll
        for(int j=0;j<8;j++)
          acc[i][j] += ra[i]*rb[j];
    }
    __syncthreads();
  }
  #pragma unroll
  for(int i=0;i<8;i++){
    int mrow = ((i>>2)<<6) + ty*4 + (i&3);
    size_t rowoff = (size_t)b*Oc*HWs + (size_t)(o0+mrow)*HWs + sp;
    float bia = bias ? bias[o0+mrow] : 0.f;
    #pragma unroll
    for(int c2=0;c2<2;c2++){
      int nc = (c2<<6) + tx*4;
      float r[4];
      #pragma unroll
      for(int q=0;q<4;q++) r[q] = acc[i][c2*4+q] + bia;
      if (resid){
        float rv[4]; load4(resid + rowoff + nc, rv);
        #pragma unroll
        for(int q=0;q<4;q++) r[q] += rv[q];
      }
      store4(out + rowoff + nc, r);
    }
  }
}

// ---------------- per-slice logit scale (q/k norms fold to a scalar) ----------------
__global__ __launch_bounds__(256) void norm_kernel(const bf* __restrict__ qkv,
    const float* __restrict__ scale, float* __restrict__ lscale){
  int s = blockIdx.x;
  int b = s >> 8, ch = s & 255;
  const bf* qp = qkv + ((size_t)b*768 + ch)*HWs;
  const bf* kp = qp + (size_t)256*HWs;
  float sq=0.f, sk=0.f;
  for(int i=threadIdx.x;i<HWs;i+=256){
    float a = b2f(qp[i]); sq += a*a;
    float c = b2f(kp[i]); sk += c*c;
  }
  __shared__ float r1[256], r2[256];
  r1[threadIdx.x]=sq; r2[threadIdx.x]=sk;
  __syncthreads();
  for(int o=128;o>0;o>>=1){
    if(threadIdx.x<o){ r1[threadIdx.x]+=r1[threadIdx.x+o]; r2[threadIdx.x]+=r2[threadIdx.x+o]; }
    __syncthreads();
  }
  if(threadIdx.x==0){
    float nq = fmaxf(sqrtf(r1[0]), 1e-12f);
    float nk = fmaxf(sqrtf(r2[0]), 1e-12f);
    // scale (NH,1,1)->(1,1,NH,1,1) broadcasts against the HD axis -> index hd = ch&15
    lscale[s] = scale[ch & 15] / (nq*nk);
  }
}

// 16B-chunk XOR swizzle: conflict-free float4 row reads at stride 128 floats
#define SW(r,c) (((((c)>>2)^((r)&7))<<2)|((c)&3))

// ---------------- axial attention, one slice (b,nh,hd) per block ----------------
template<int DIR, int ACCUM>
__global__ __launch_bounds__(256) void attn_kernel(const bf* __restrict__ qkv,
    const float* __restrict__ lscale, bf* __restrict__ attnf){
  __shared__ float S0[128][128];   // 64 KiB
  __shared__ float S1[128][128];   // 64 KiB  (total 128 KiB exactly)
  int s  = blockIdx.x;
  int b  = s >> 8;
  int ch = s & 255;
  const bf* qp = qkv + ((size_t)b*768 + ch)*HWs;
  const bf* kp = qp + (size_t)256*HWs;
  const bf* vp = qp + (size_t)512*HWs;
  int t = threadIdx.x;
  float ls = lscale[s];
  for(int i=0;i<64;i++){
    int idx = i*256 + t;
    int r = idx >> 7, c = idx & 127;
    float qv = b2f(qp[idx]), kv = b2f(kp[idx]);
    if (DIR==0){ S0[r][SW(r,c)]=qv; S1[r][SW(r,c)]=kv; }
    else       { S0[c][SW(c,r)]=qv; S1[c][SW(c,r)]=kv; }
  }
  __syncthreads();
  int g = t >> 3, l = t & 7;
  float a[4][16];
  #pragma unroll
  for(int i=0;i<4;i++)
    #pragma unroll
    for(int j=0;j<16;j++) a[i][j]=0.f;
  // phase 1: A[r][z] = sum_y S0[r][y]*S1[z][y];  r_i = g+32i, z_j = l+8j
  for(int y0=0;y0<128;y0+=4){
    float4 q4[4], k4[16];
    #pragma unroll
    for(int i=0;i<4;i++){ int rr=g+32*i; q4[i] = *(const float4*)&S0[rr][SW(rr,y0)]; }
    #pragma unroll
    for(int j=0;j<16;j++){ int rr=l+8*j; k4[j] = *(const float4*)&S1[rr][SW(rr,y0)]; }
    #pragma unroll
    for(int i=0;i<4;i++)
      #pragma unroll
      for(int j=0;j<16;j++)
        a[i][j] += q4[i].x*k4[j].x + q4[i].y*k4[j].y + q4[i].z*k4[j].z + q4[i].w*k4[j].w;
  }
  // softmax per row (row spread over 8 threads: l = t&7)
  #pragma unroll
  for(int i=0;i<4;i++){
    float m = -1e30f;
    #pragma unroll
    for(int j=0;j<16;j++){ a[i][j] *= ls; m = fmaxf(m, a[i][j]); }
    m = fmaxf(m, __shfl_xor(m, 1));
    m = fmaxf(m, __shfl_xor(m, 2));
    m = fmaxf(m, __shfl_xor(m, 4));
    float sum = 0.f;
    #pragma unroll
    for(int j=0;j<16;j++){ a[i][j] = __expf(a[i][j]-m); sum += a[i][j]; }
    sum += __shfl_xor(sum, 1);
    sum += __shfl_xor(sum, 2);
    sum += __shfl_xor(sum, 4);
    float inv = 1.0f/sum;
    #pragma unroll
    for(int j=0;j<16;j++) a[i][j] *= inv;
  }
  __syncthreads();
  // P -> S0, V -> S1
  #pragma unroll
  for(int i=0;i<4;i++){
    int rr = g+32*i;
    #pragma unroll
    for(int j=0;j<16;j++)
      S0[rr][SW(rr, l+8*j)] = a[i][j];
  }
  for(int i=0;i<64;i++){
    int idx = i*256 + t;
    int r = idx >> 7, c = idx & 127;
    float vv = b2f(vp[idx]);
    if (DIR==0) S1[r][SW(r,c)]=vv; else S1[c][SW(c,r)]=vv;
  }
  __syncthreads();
  // phase 2: O[r][y] = sum_z P[r][z]*S1[z][y]
  float o[4][16];
  #pragma unroll
  for(int i=0;i<4;i++)
    #pragma unroll
    for(int j=0;j<16;j++) o[i][j]=0.f;
  for(int z0=0;z0<128;z0+=4){
    float4 p4[4];
    #pragma unroll
    for(int i=0;i<4;i++){ int rr=g+32*i; p4[i] = *(const float4*)&S0[rr][SW(rr,z0)]; }
    float4 v4[4][4];
    #pragma unroll
    for(int zz=0;zz<4;zz++){
      int rr = z0+zz;
      #pragma unroll
      for(int jj=0;jj<4;jj++)
        v4[zz][jj] = *(const float4*)&S1[rr][SW(rr, jj*32 + l*4)];
    }
    #pragma unroll
    for(int i=0;i<4;i++){
      float pz[4] = {p4[i].x, p4[i].y, p4[i].z, p4[i].w};
      #pragma unroll
      for(int zz=0;zz<4;zz++)
        #pragma unroll
        for(int jj=0;jj<4;jj++){
          o[i][jj*4+0] += pz[zz]*v4[zz][jj].x;
          o[i][jj*4+1] += pz[zz]*v4[zz][jj].y;
          o[i][jj*4+2] += pz[zz]*v4[zz][jj].z;
          o[i][jj*4+3] += pz[zz]*v4[zz][jj].w;
        }
    }
  }
  __syncthreads();
  // stage output in S0, then write coalesced (transposed back for DIR 1)
  #pragma unroll
  for(int i=0;i<4;i++){
    int rr = g+32*i;
    #pragma unroll
    for(int jj=0;jj<4;jj++)
      *(float4*)&S0[rr][SW(rr, jj*32+l*4)] =
        make_float4(o[i][jj*4+0],o[i][jj*4+1],o[i][jj*4+2],o[i][jj*4+3]);
  }
  __syncthreads();
  bf* op = attnf + ((size_t)b*DIMC + ch)*HWs;
  for(int i=0;i<64;i++){
    int idx = i*256 + t;
    int r = idx >> 7, c = idx & 127;
    float val = (DIR==0) ? S0[r][SW(r,c)] : S0[c][SW(c,r)];
    if (ACCUM) op[idx] = f2b(b2f(op[idx]) + val);
    else       op[idx] = f2b(val);
  }
}

// ---------------- launch ----------------
extern "C" void kernel_launch(void* const* d_in, const int* in_sizes, int n_in,
                              void* d_out, int out_size, void* d_ws, size_t ws_size,
                              hipStream_t stream){
  (void)in_sizes; (void)n_in; (void)out_size; (void)ws_size;
  const float* x       = (const float*)d_in[0];
  const float* ln1_w   = (const float*)d_in[1];
  const float* ln1_b   = (const float*)d_in[2];
  const float* conv3_w = (const float*)d_in[3];
  const float* conv3_b = (const float*)d_in[4];
  const float* conv5_w = (const float*)d_in[5];
  const float* conv5_b = (const float*)d_in[6];
  const float* qkv_w   = (const float*)d_in[7];
  const float* scale   = (const float*)d_in[8];
  const float* g1_w    = (const float*)d_in[9];
  const float* g1_b    = (const float*)d_in[10];
  const float* g2_w    = (const float*)d_in[11];
  const float* g2_b    = (const float*)d_in[12];
  const float* proj_w  = (const float*)d_in[13];
  const float* proj_b  = (const float*)d_in[14];
  const float* ln2_w   = (const float*)d_in[15];
  const float* ln2_b   = (const float*)d_in[16];
  const float* pin_w   = (const float*)d_in[17];
  const float* dw_w    = (const float*)d_in[18];
  const float* pout_w  = (const float*)d_in[19];
  float* out = (float*)d_out;
  char* wsb  = (char*)d_ws;

  // bf16 intermediates, liveness-aliased: peak ws = 160 MB + 16 KB
  const size_t MB = 1024*1024;
  bf* y    = (bf*)(wsb +   0*MB);   // 32 MB   [dead after qkv gemm]
  bf* conv = (bf*)(wsb +  32*MB);   // 32 MB   [dead after proj gemm]
  bf* qkv  = (bf*)(wsb +  64*MB);   // 96 MB   [dead after attn]
  bf* attn = (bf*)(wsb +   0*MB);   // 32 MB   (aliases y)      [dead after proj]
  bf* xnew = (bf*)(wsb +  64*MB);   // 32 MB   (aliases qkv[0]) [live to end]
  bf* y2   = (bf*)(wsb +  96*MB);   // 32 MB   (aliases qkv[1]) [dead after pin]
  bf* p    = (bf*)(wsb +   0*MB);   // 64 MB   (aliases attn+conv) [dead after dwconv2]
  bf* dwo  = (bf*)(wsb +  96*MB);   // 64 MB   (aliases y2+qkv[2]) [dead after pout]
  float* gp     = (float*)(wsb + 160*MB);
  float* cwaw   = gp + 1024;
  float* lscale = cwaw + 16;

  ln_kernel<float><<<256,256,0,stream>>>(x, ln1_w, ln1_b, y);
  gp_kernel<<<1024,256,0,stream>>>(y, gp);
  gate_kernel<<<1,256,0,stream>>>(gp, g1_w, g1_b, g2_w, g2_b, cwaw);
  dwconv_kernel<<<65536,256,0,stream>>>(y, conv3_w, conv3_b, conv5_w, conv5_b, conv);
  gemm_kernel<0,float,bf><<<dim3(512,6),256,0,stream>>>(qkv_w, y, nullptr, nullptr,
                                               nullptr, nullptr, qkv, 256, 256, 768);
  norm_kernel<<<1024,256,0,stream>>>(qkv, scale, lscale);
  attn_kernel<0,0><<<1024,256,0,stream>>>(qkv, lscale, attn);
  attn_kernel<1,1><<<1024,256,0,stream>>>(qkv, lscale, attn);
  gemm_kernel<1,float,bf><<<dim3(512,2),256,0,stream>>>(proj_w, conv, attn, cwaw,
                                               proj_b, x, xnew, 256, 256, 256);
  ln_kernel<bf><<<256,256,0,stream>>>(xnew, ln2_w, ln2_b, y2);
  gemm_kernel<0,float,bf><<<dim3(512,4),256,0,stream>>>(pin_w, y2, nullptr, nullptr,
                                               nullptr, nullptr, p, 256, 256, 512);
  dwconv2_kernel<<<131072,256,0,stream>>>(p, dw_w, dwo);
  gemm_kernel<2,bf,float><<<dim3(512,2),256,0,stream>>>(pout_w, dwo, nullptr, nullptr,
                                               nullptr, xnew, out, 256, 512, 256);
}

// Round 3
// 1143.722 us; speedup vs baseline: 1.4022x; 1.4022x over previous
//
#include <hip/hip_runtime.h>
#include <hip/hip_bf16.h>
#include <math.h>

#define DIMC 256
#define NB   4
#define HH   128
#define WW   128
#define HWs  16384
#define HID  256
#define C2   512
#define EPSf 1e-5f

typedef __hip_bfloat16 bf;
typedef unsigned short u16;
typedef unsigned int   u32;
typedef float f32x4 __attribute__((ext_vector_type(4)));
typedef u32   u32x4 __attribute__((ext_vector_type(4)));

__device__ __forceinline__ float b2f(bf v){ return __bfloat162float(v); }
__device__ __forceinline__ bf    f2b(float v){ return __float2bfloat16(v); }
__device__ __forceinline__ float ldf(const float* p){ return *p; }
__device__ __forceinline__ float ldf(const bf* p){ return __bfloat162float(*p); }
__device__ __forceinline__ void  sto(float* p, float v){ *p = v; }
__device__ __forceinline__ void  sto(bf* p, float v){ *p = f2b(v); }

__device__ __forceinline__ float gelu_exact(float v){
  return 0.5f*v*(1.0f + erff(v*0.70710678118654752f));
}

// ---------------- weight fp32 -> bf16 convert ----------------
__global__ __launch_bounds__(256) void cvt_kernel(const float* __restrict__ s,
    u16* __restrict__ d, int n){
  int i = blockIdx.x*256 + threadIdx.x;
  if (i < n){ bf h = f2b(s[i]); d[i] = *(u16*)&h; }
}

// ---------------- LayerNorm over channel dim (per pixel), bf16 out ----------------
template<typename TI>
__global__ __launch_bounds__(256) void ln_kernel(const TI* __restrict__ x,
    const float* __restrict__ w, const float* __restrict__ bb, bf* __restrict__ y){
  int p = blockIdx.x*256 + threadIdx.x;
  int b  = p >> 14;
  int sp = p & (HWs-1);
  const TI* xb = x + (size_t)b*DIMC*HWs + sp;
  float s = 0.f, s2 = 0.f;
  for(int c=0;c<DIMC;c++){ float v = ldf(xb + (size_t)c*HWs); s += v; s2 += v*v; }
  float mu   = s * (1.0f/DIMC);
  float var  = s2 * (1.0f/DIMC) - mu*mu;
  float rinv = rsqrtf(var + EPSf);
  bf* yb = y + (size_t)b*DIMC*HWs + sp;
  for(int c=0;c<DIMC;c++){
    float v = ldf(xb + (size_t)c*HWs);
    yb[(size_t)c*HWs] = f2b((v - mu)*rinv*w[c] + bb[c]);
  }
}

// ---------------- global average pool per (b,c) ----------------
__global__ __launch_bounds__(256) void gp_kernel(const bf* __restrict__ y, float* __restrict__ gp){
  int bc = blockIdx.x;
  const bf* pl = y + (size_t)bc*HWs;
  float s = 0.f;
  for(int i=threadIdx.x;i<HWs;i+=256) s += b2f(pl[i]);
  __shared__ float red[256];
  red[threadIdx.x] = s; __syncthreads();
  for(int o=128;o>0;o>>=1){
    if(threadIdx.x<o) red[threadIdx.x] += red[threadIdx.x+o];
    __syncthreads();
  }
  if(threadIdx.x==0) gp[bc] = red[0]*(1.0f/HWs);
}

// ---------------- gating MLP (tiny) ----------------
__global__ __launch_bounds__(256) void gate_kernel(const float* __restrict__ gp,
    const float* __restrict__ g1w, const float* __restrict__ g1b,
    const float* __restrict__ g2w, const float* __restrict__ g2b,
    float* __restrict__ cwaw){
  __shared__ float h[NB][64];
  __shared__ float zz[NB][2];
  int t = threadIdx.x;
  int b = t >> 6, j = t & 63;
  const float* gpb = gp + b*DIMC;
  const float* wr  = g1w + j*DIMC;
  float s = g1b[j];
  for(int c=0;c<DIMC;c++) s += gpb[c]*wr[c];
  h[b][j] = fmaxf(s, 0.f);
  __syncthreads();
  if (t < 8){
    int b2 = t >> 1, o = t & 1;
    float z = g2b[o];
    const float* w2 = g2w + o*64;
    for(int q=0;q<64;q++) z += w2[q]*h[b2][q];
    zz[b2][o] = z;
  }
  __syncthreads();
  if (t < 4){
    float z0 = zz[t][0], z1 = zz[t][1];
    float mm = fmaxf(z0,z1);
    float e0 = __expf(z0-mm), e1 = __expf(z1-mm);
    float inv = 1.0f/(e0+e1);
    cwaw[2*t]   = e0*inv;
    cwaw[2*t+1] = e1*inv;
  }
}

// ---------------- depthwise conv 3x3 + 5x5 + biases ----------------
__global__ __launch_bounds__(256) void dwconv_kernel(const bf* __restrict__ y,
    const float* __restrict__ w3, const float* __restrict__ b3,
    const float* __restrict__ w5, const float* __restrict__ b5,
    bf* __restrict__ out){
  int idx = blockIdx.x*256 + threadIdx.x;
  int wx = idx & 127;
  int rest = idx >> 7;
  int hy = rest & 127; rest >>= 7;
  int c  = rest & 255;
  int b  = rest >> 8;
  const bf* pl = y + ((size_t)b*DIMC + c)*HWs;
  const float* k3 = w3 + c*9;
  const float* k5 = w5 + c*25;
  float acc = b3[c] + b5[c];
  #pragma unroll
  for(int di=-2; di<=2; di++){
    int yy = hy + di;
    if((unsigned)yy >= (unsigned)HH) continue;
    const bf* prow = pl + yy*WW;
    #pragma unroll
    for(int dj=-2; dj<=2; dj++){
      int xx = wx + dj;
      if((unsigned)xx >= (unsigned)WW) continue;
      float v = b2f(prow[xx]);
      acc += v * k5[(di+2)*5 + (dj+2)];
      if (di>=-1 && di<=1 && dj>=-1 && dj<=1)
        acc += v * k3[(di+1)*3 + (dj+1)];
    }
  }
  out[idx] = f2b(acc);
}

// ---------------- grouped conv (2-2 per group, 3x3) fused with GLU ----------------
// computes dwo channel o (x1) and o+256 (x2); writes m = gelu(x1)*x2
__global__ __launch_bounds__(256) void dwconv2_glu_kernel(const bf* __restrict__ p,
    const float* __restrict__ w, bf* __restrict__ m){
  int idx = blockIdx.x*256 + threadIdx.x;        // NB*HID*HWs
  int wx = idx & 127;
  int rest = idx >> 7;
  int hy = rest & 127; rest >>= 7;
  int o  = rest & 255;
  int b  = rest >> 8;
  int gi = o & ~1;
  const bf* p0 = p + ((size_t)b*C2 + gi)*HWs;
  const bf* p1 = p0 + HWs;
  const bf* p2 = p0 + (size_t)256*HWs;
  const bf* p3 = p2 + HWs;
  const float* k0 = w + o*18;
  const float* k1 = k0 + 9;
  const float* k2 = w + (o+256)*18;
  const float* k3 = k2 + 9;
  float a1 = 0.f, a2 = 0.f;
  #pragma unroll
  for(int di=-1; di<=1; di++){
    int yy = hy + di;
    if((unsigned)yy >= (unsigned)HH) continue;
    int roff = yy*WW;
    #pragma unroll
    for(int dj=-1; dj<=1; dj++){
      int xx = wx + dj;
      if((unsigned)xx >= (unsigned)WW) continue;
      int ki = (di+1)*3 + (dj+1);
      a1 += b2f(p0[roff+xx])*k0[ki] + b2f(p1[roff+xx])*k1[ki];
      a2 += b2f(p2[roff+xx])*k2[ki] + b2f(p3[roff+xx])*k3[ki];
    }
  }
  m[idx] = f2b(gelu_exact(a1)*a2);
}

// ---------------- bf16 MFMA GEMM: out[b,o,n] = sum_k W[o,k]*act[b,k,n] ----------------
// W: bf16 [Oc][256]; act: bf16 [b][256][HWs]; K=256 fixed.
// tile 128x128, 4 waves (2x2), 4x4 frags of 16x16x32; B LDS-transposed, A direct L2.
template<typename TRES, typename TOUT>
__global__ __launch_bounds__(256, 2) void mfma_gemm(
    const u16* __restrict__ Wb, const bf* __restrict__ act,
    const float* __restrict__ bias, const TRES* __restrict__ resid,
    TOUT* __restrict__ out, int Oc)
{
  __shared__ u16 Bs[2][4096];        // [n:128][k:32] bf16, double-buffered
  int t  = threadIdx.x;
  int n0 = blockIdx.x * 128;
  int o0 = blockIdx.y * 128;
  int b  = n0 >> 14;
  int sp = n0 & (HWs-1);
  const u16* actu = (const u16*)act + (size_t)b*256*HWs + sp;

  int kp = t & 15;                   // k-pair (rows 2kp, 2kp+1)
  int ns = (t >> 4) << 3;            // n-start for staging strip
  int lane = t & 63;
  int wv = t >> 6;
  int wr = (wv >> 1) << 6;           // wave o-offset
  int wc = (wv & 1) << 6;            // wave n-offset
  int fr = lane & 15;                // fragment row/col
  int kg = lane >> 4;                // k-group (8 bf16 each)

  f32x4 acc[4][4] = {};

  auto stage = [&](int ks, int buf){
    const u16* r0 = actu + (size_t)(ks*32 + 2*kp)*HWs + ns;
    u32x4 u = *(const u32x4*)r0;
    u32x4 v = *(const u32x4*)(r0 + HWs);
    u32 w0=(u.x&0xffffu)|(v.x<<16), w1=(u.x>>16)|(v.x&0xffff0000u);
    u32 w2=(u.y&0xffffu)|(v.y<<16), w3=(u.y>>16)|(v.y&0xffff0000u);
    u32 w4=(u.z&0xffffu)|(v.z<<16), w5=(u.z>>16)|(v.z&0xffff0000u);
    u32 w6=(u.w&0xffffu)|(v.w<<16), w7=(u.w>>16)|(v.w&0xffff0000u);
    u16* bp = Bs[buf];
    int c0 = kp*2;
    *(u32*)&bp[(ns+0)*32+c0]=w0; *(u32*)&bp[(ns+1)*32+c0]=w1;
    *(u32*)&bp[(ns+2)*32+c0]=w2; *(u32*)&bp[(ns+3)*32+c0]=w3;
    *(u32*)&bp[(ns+4)*32+c0]=w4; *(u32*)&bp[(ns+5)*32+c0]=w5;
    *(u32*)&bp[(ns+6)*32+c0]=w6; *(u32*)&bp[(ns+7)*32+c0]=w7;
  };

  stage(0, 0);
  #pragma unroll
  for(int ks=0; ks<8; ++ks){
    int cur = ks & 1;
    __syncthreads();
    if (ks < 7) stage(ks+1, cur^1);
    u32x4 af[4], bfr[4];
    #pragma unroll
    for(int i=0;i<4;i++)
      af[i] = *(const u32x4*)(Wb + (size_t)(o0+wr+i*16+fr)*256 + ks*32 + kg*8);
    #pragma unroll
    for(int j=0;j<4;j++)
      bfr[j] = *(const u32x4*)&Bs[cur][(wc + j*16 + fr)*32 + kg*8];
    #pragma unroll
    for(int i=0;i<4;i++)
      #pragma unroll
      for(int j=0;j<4;j++)
        asm("v_mfma_f32_16x16x32_bf16 %0, %1, %2, %0"
            : "+v"(acc[i][j]) : "v"(af[i]), "v"(bfr[j]));
  }
  asm volatile("s_nop 7\n\ts_nop 7");   // MFMA->VALU read hazard guard

  // epilogue: C/D layout col=lane&15, row=(lane>>4)*4+reg  [m89-verified]
  #pragma unroll
  for(int i=0;i<4;i++){
    #pragma unroll
    for(int reg=0;reg<4;reg++){
      int o = o0 + wr + i*16 + kg*4 + reg;
      size_t rowoff = ((size_t)b*Oc + o)*HWs + sp + wc + fr;
      float bia = bias ? bias[o] : 0.f;
      #pragma unroll
      for(int j=0;j<4;j++){
        float val = acc[i][j][reg] + bia;
        size_t pidx = rowoff + (size_t)(j*16);
        if (resid) val += ldf(resid + pidx);
        sto(out + pidx, val);
      }
    }
  }
}

// ---------------- per-slice logit scale (q/k norms fold to a scalar) ----------------
__global__ __launch_bounds__(256) void norm_kernel(const bf* __restrict__ qkv,
    const float* __restrict__ scale, float* __restrict__ lscale){
  int s = blockIdx.x;
  int b = s >> 8, ch = s & 255;
  const bf* qp = qkv + ((size_t)b*768 + ch)*HWs;
  const bf* kp = qp + (size_t)256*HWs;
  float sq=0.f, sk=0.f;
  for(int i=threadIdx.x;i<HWs;i+=256){
    float a = b2f(qp[i]); sq += a*a;
    float c = b2f(kp[i]); sk += c*c;
  }
  __shared__ float r1[256], r2[256];
  r1[threadIdx.x]=sq; r2[threadIdx.x]=sk;
  __syncthreads();
  for(int o=128;o>0;o>>=1){
    if(threadIdx.x<o){ r1[threadIdx.x]+=r1[threadIdx.x+o]; r2[threadIdx.x]+=r2[threadIdx.x+o]; }
    __syncthreads();
  }
  if(threadIdx.x==0){
    float nq = fmaxf(sqrtf(r1[0]), 1e-12f);
    float nk = fmaxf(sqrtf(r2[0]), 1e-12f);
    lscale[s] = scale[ch & 15] / (nq*nk);
  }
}

// 16B-chunk XOR swizzle: conflict-free float4 row reads at stride 128 floats
#define SW(r,c) (((((c)>>2)^((r)&7))<<2)|((c)&3))

// ---------------- axial attention, one slice (b,nh,hd) per block ----------------
// MIX (dir1): writes cw*conv + aw*(out_h+out_v)
template<int DIR, int MIX>
__global__ __launch_bounds__(256) void attn_kernel(const bf* __restrict__ qkv,
    const float* __restrict__ lscale, bf* __restrict__ attnf,
    const bf* __restrict__ conv, const float* __restrict__ cwaw){
  __shared__ float S0[128][128];
  __shared__ float S1[128][128];
  int s  = blockIdx.x;
  int b  = s >> 8;
  int ch = s & 255;
  const bf* qp = qkv + ((size_t)b*768 + ch)*HWs;
  const bf* kp = qp + (size_t)256*HWs;
  const bf* vp = qp + (size_t)512*HWs;
  int t = threadIdx.x;
  float ls = lscale[s];
  for(int i=0;i<64;i++){
    int idx = i*256 + t;
    int r = idx >> 7, c = idx & 127;
    float qv = b2f(qp[idx]), kv = b2f(kp[idx]);
    if (DIR==0){ S0[r][SW(r,c)]=qv; S1[r][SW(r,c)]=kv; }
    else       { S0[c][SW(c,r)]=qv; S1[c][SW(c,r)]=kv; }
  }
  __syncthreads();
  int g = t >> 3, l = t & 7;
  float a[4][16];
  #pragma unroll
  for(int i=0;i<4;i++)
    #pragma unroll
    for(int j=0;j<16;j++) a[i][j]=0.f;
  for(int y0=0;y0<128;y0+=4){
    float4 q4[4], k4[16];
    #pragma unroll
    for(int i=0;i<4;i++){ int rr=g+32*i; q4[i] = *(const float4*)&S0[rr][SW(rr,y0)]; }
    #pragma unroll
    for(int j=0;j<16;j++){ int rr=l+8*j; k4[j] = *(const float4*)&S1[rr][SW(rr,y0)]; }
    #pragma unroll
    for(int i=0;i<4;i++)
      #pragma unroll
      for(int j=0;j<16;j++)
        a[i][j] += q4[i].x*k4[j].x + q4[i].y*k4[j].y + q4[i].z*k4[j].z + q4[i].w*k4[j].w;
  }
  #pragma unroll
  for(int i=0;i<4;i++){
    float m = -1e30f;
    #pragma unroll
    for(int j=0;j<16;j++){ a[i][j] *= ls; m = fmaxf(m, a[i][j]); }
    m = fmaxf(m, __shfl_xor(m, 1));
    m = fmaxf(m, __shfl_xor(m, 2));
    m = fmaxf(m, __shfl_xor(m, 4));
    float sum = 0.f;
    #pragma unroll
    for(int j=0;j<16;j++){ a[i][j] = __expf(a[i][j]-m); sum += a[i][j]; }
    sum += __shfl_xor(sum, 1);
    sum += __shfl_xor(sum, 2);
    sum += __shfl_xor(sum, 4);
    float inv = 1.0f/sum;
    #pragma unroll
    for(int j=0;j<16;j++) a[i][j] *= inv;
  }
  __syncthreads();
  #pragma unroll
  for(int i=0;i<4;i++){
    int rr = g+32*i;
    #pragma unroll
    for(int j=0;j<16;j++)
      S0[rr][SW(rr, l+8*j)] = a[i][j];
  }
  for(int i=0;i<64;i++){
    int idx = i*256 + t;
    int r = idx >> 7, c = idx & 127;
    float vv = b2f(vp[idx]);
    if (DIR==0) S1[r][SW(r,c)]=vv; else S1[c][SW(c,r)]=vv;
  }
  __syncthreads();
  float o[4][16];
  #pragma unroll
  for(int i=0;i<4;i++)
    #pragma unroll
    for(int j=0;j<16;j++) o[i][j]=0.f;
  for(int z0=0;z0<128;z0+=4){
    float4 p4[4];
    #pragma unroll
    for(int i=0;i<4;i++){ int rr=g+32*i; p4[i] = *(const float4*)&S0[rr][SW(rr,z0)]; }
    float4 v4[4][4];
    #pragma unroll
    for(int zz=0;zz<4;zz++){
      int rr = z0+zz;
      #pragma unroll
      for(int jj=0;jj<4;jj++)
        v4[zz][jj] = *(const float4*)&S1[rr][SW(rr, jj*32 + l*4)];
    }
    #pragma unroll
    for(int i=0;i<4;i++){
      float pz[4] = {p4[i].x, p4[i].y, p4[i].z, p4[i].w};
      #pragma unroll
      for(int zz=0;zz<4;zz++)
        #pragma unroll
        for(int jj=0;jj<4;jj++){
          o[i][jj*4+0] += pz[zz]*v4[zz][jj].x;
          o[i][jj*4+1] += pz[zz]*v4[zz][jj].y;
          o[i][jj*4+2] += pz[zz]*v4[zz][jj].z;
          o[i][jj*4+3] += pz[zz]*v4[zz][jj].w;
        }
    }
  }
  __syncthreads();
  #pragma unroll
  for(int i=0;i<4;i++){
    int rr = g+32*i;
    #pragma unroll
    for(int jj=0;jj<4;jj++)
      *(float4*)&S0[rr][SW(rr, jj*32+l*4)] =
        make_float4(o[i][jj*4+0],o[i][jj*4+1],o[i][jj*4+2],o[i][jj*4+3]);
  }
  __syncthreads();
  bf* op = attnf + ((size_t)b*DIMC + ch)*HWs;
  if (MIX){
    float cw = cwaw[2*b], aw = cwaw[2*b+1];
    const bf* cp = conv + ((size_t)b*DIMC + ch)*HWs;
    for(int i=0;i<64;i++){
      int idx = i*256 + t;
      int r = idx >> 7, c = idx & 127;
      float val = (DIR==0) ? S0[r][SW(r,c)] : S0[c][SW(c,r)];
      op[idx] = f2b(cw*b2f(cp[idx]) + aw*(b2f(op[idx]) + val));
    }
  } else {
    for(int i=0;i<64;i++){
      int idx = i*256 + t;
      int r = idx >> 7, c = idx & 127;
      float val = (DIR==0) ? S0[r][SW(r,c)] : S0[c][SW(c,r)];
      op[idx] = f2b(val);
    }
  }
}

// ---------------- launch ----------------
extern "C" void kernel_launch(void* const* d_in, const int* in_sizes, int n_in,
                              void* d_out, int out_size, void* d_ws, size_t ws_size,
                              hipStream_t stream){
  (void)in_sizes; (void)n_in; (void)out_size; (void)ws_size;
  const float* x       = (const float*)d_in[0];
  const float* ln1_w   = (const float*)d_in[1];
  const float* ln1_b   = (const float*)d_in[2];
  const float* conv3_w = (const float*)d_in[3];
  const float* conv3_b = (const float*)d_in[4];
  const float* conv5_w = (const float*)d_in[5];
  const float* conv5_b = (const float*)d_in[6];
  const float* qkv_w   = (const float*)d_in[7];
  const float* scale   = (const float*)d_in[8];
  const float* g1_w    = (const float*)d_in[9];
  const float* g1_b    = (const float*)d_in[10];
  const float* g2_w    = (const float*)d_in[11];
  const float* g2_b    = (const float*)d_in[12];
  const float* proj_w  = (const float*)d_in[13];
  const float* proj_b  = (const float*)d_in[14];
  const float* ln2_w   = (const float*)d_in[15];
  const float* ln2_b   = (const float*)d_in[16];
  const float* pin_w   = (const float*)d_in[17];
  const float* dw_w    = (const float*)d_in[18];
  const float* pout_w  = (const float*)d_in[19];
  float* out = (float*)d_out;
  char* wsb  = (char*)d_ws;

  const size_t MB = 1024*1024;
  bf* y    = (bf*)(wsb +   0*MB);   // 32 MB  [dead after qkv gemm]
  bf* conv = (bf*)(wsb +  32*MB);   // 32 MB  [dead after attn1]
  bf* qkv  = (bf*)(wsb +  64*MB);   // 96 MB  [dead after attn]
  bf* attnf= (bf*)(wsb +   0*MB);   // 32 MB  (aliases y)   [mixed; dead after proj]
  bf* xnew = (bf*)(wsb +  64*MB);   // 32 MB  (aliases qkv) [live to end]
  bf* y2   = (bf*)(wsb +  96*MB);   // 32 MB  (aliases qkv) [dead after pin]
  bf* p    = (bf*)(wsb +   0*MB);   // 64 MB  [dead after dwconv2_glu]
  bf* m    = (bf*)(wsb +  96*MB);   // 32 MB  (aliases y2)  [dead after pout]
  u16* Wqkv  = (u16*)(wsb + 160*MB);        // 384 KB
  u16* Wproj = Wqkv + 196608;               // 128 KB
  u16* Wpin  = Wproj + 65536;               // 256 KB
  u16* Wpout = Wpin + 131072;               // 128 KB
  float* gp     = (float*)(Wpout + 65536);
  float* cwaw   = gp + 1024;
  float* lscale = cwaw + 16;

  cvt_kernel<<<768,256,0,stream>>>(qkv_w,  Wqkv, 196608);
  cvt_kernel<<<256,256,0,stream>>>(proj_w, Wproj, 65536);
  cvt_kernel<<<512,256,0,stream>>>(pin_w,  Wpin, 131072);
  cvt_kernel<<<256,256,0,stream>>>(pout_w, Wpout, 65536);

  ln_kernel<float><<<256,256,0,stream>>>(x, ln1_w, ln1_b, y);
  gp_kernel<<<1024,256,0,stream>>>(y, gp);
  gate_kernel<<<1,256,0,stream>>>(gp, g1_w, g1_b, g2_w, g2_b, cwaw);
  dwconv_kernel<<<65536,256,0,stream>>>(y, conv3_w, conv3_b, conv5_w, conv5_b, conv);
  mfma_gemm<float,bf><<<dim3(512,6),256,0,stream>>>(Wqkv, y, nullptr,
                                        (const float*)nullptr, qkv, 768);
  norm_kernel<<<1024,256,0,stream>>>(qkv, scale, lscale);
  attn_kernel<0,0><<<1024,256,0,stream>>>(qkv, lscale, attnf, nullptr, nullptr);
  attn_kernel<1,1><<<1024,256,0,stream>>>(qkv, lscale, attnf, conv, cwaw);
  mfma_gemm<float,bf><<<dim3(512,2),256,0,stream>>>(Wproj, attnf, proj_b, x, xnew, 256);
  ln_kernel<bf><<<256,256,0,stream>>>(xnew, ln2_w, ln2_b, y2);
  mfma_gemm<float,bf><<<dim3(512,4),256,0,stream>>>(Wpin, y2, nullptr,
                                        (const float*)nullptr, p, 512);
  dwconv2_glu_kernel<<<65536,256,0,stream>>>(p, dw_w, m);
  mfma_gemm<bf,float><<<dim3(512,2),256,0,stream>>>(Wpout, m, nullptr, xnew, out, 256);
}

// Round 5
// 793.651 us; speedup vs baseline: 2.0207x; 1.4411x over previous
//
#include <hip/hip_runtime.h>
#include <hip/hip_bf16.h>
#include <math.h>

#define DIMC 256
#define NB   4
#define HH   128
#define WW   128
#define HWs  16384
#define HID  256
#define C2   512
#define EPSf 1e-5f

typedef __hip_bfloat16 bf;
typedef unsigned short u16;
typedef unsigned int   u32;
typedef float f32x4  __attribute__((ext_vector_type(4)));
typedef u32   u32x4  __attribute__((ext_vector_type(4)));
typedef short bf16x8 __attribute__((ext_vector_type(8)));

__device__ __forceinline__ float b2f(bf v){ return __bfloat162float(v); }
__device__ __forceinline__ bf    f2b(float v){ return __float2bfloat16(v); }
__device__ __forceinline__ float ldf(const float* p){ return *p; }
__device__ __forceinline__ float ldf(const bf* p){ return __bfloat162float(*p); }
__device__ __forceinline__ void  sto(float* p, float v){ *p = v; }
__device__ __forceinline__ void  sto(bf* p, float v){ *p = f2b(v); }
__device__ __forceinline__ void unpack2(u32 u, float& a, float& b){
  union{u32 x; float f;} lo, hi;
  lo.x = u << 16; hi.x = u & 0xffff0000u;
  a = lo.f; b = hi.f;
}
__device__ __forceinline__ u32 pack2(float a, float b){
  bf h0 = f2b(a), h1 = f2b(b);
  return (u32)*(u16*)&h0 | ((u32)*(u16*)&h1 << 16);
}

__device__ __forceinline__ float gelu_exact(float v){
  return 0.5f*v*(1.0f + erff(v*0.70710678118654752f));
}

// ---------------- weight fp32 -> bf16 convert ----------------
__global__ __launch_bounds__(256) void cvt_kernel(const float* __restrict__ s,
    u16* __restrict__ d, int n){
  int i = blockIdx.x*256 + threadIdx.x;
  if (i < n){ bf h = f2b(s[i]); d[i] = *(u16*)&h; }
}

// ---------------- LayerNorm over channel dim (per pixel), bf16 out ----------------
template<typename TI>
__global__ __launch_bounds__(256) void ln_kernel(const TI* __restrict__ x,
    const float* __restrict__ w, const float* __restrict__ bb, bf* __restrict__ y){
  int p = blockIdx.x*256 + threadIdx.x;
  int b  = p >> 14;
  int sp = p & (HWs-1);
  const TI* xb = x + (size_t)b*DIMC*HWs + sp;
  float s = 0.f, s2 = 0.f;
  for(int c=0;c<DIMC;c++){ float v = ldf(xb + (size_t)c*HWs); s += v; s2 += v*v; }
  float mu   = s * (1.0f/DIMC);
  float var  = s2 * (1.0f/DIMC) - mu*mu;
  float rinv = rsqrtf(var + EPSf);
  bf* yb = y + (size_t)b*DIMC*HWs + sp;
  for(int c=0;c<DIMC;c++){
    float v = ldf(xb + (size_t)c*HWs);
    yb[(size_t)c*HWs] = f2b((v - mu)*rinv*w[c] + bb[c]);
  }
}

// ---------------- global average pool per (b,c) ----------------
__global__ __launch_bounds__(256) void gp_kernel(const bf* __restrict__ y, float* __restrict__ gp){
  int bc = blockIdx.x;
  const bf* pl = y + (size_t)bc*HWs;
  float s = 0.f;
  for(int i=threadIdx.x;i<HWs;i+=256) s += b2f(pl[i]);
  __shared__ float red[256];
  red[threadIdx.x] = s; __syncthreads();
  for(int o=128;o>0;o>>=1){
    if(threadIdx.x<o) red[threadIdx.x] += red[threadIdx.x+o];
    __syncthreads();
  }
  if(threadIdx.x==0) gp[bc] = red[0]*(1.0f/HWs);
}

// ---------------- gating MLP (tiny) ----------------
__global__ __launch_bounds__(256) void gate_kernel(const float* __restrict__ gp,
    const float* __restrict__ g1w, const float* __restrict__ g1b,
    const float* __restrict__ g2w, const float* __restrict__ g2b,
    float* __restrict__ cwaw){
  __shared__ float h[NB][64];
  __shared__ float zz[NB][2];
  int t = threadIdx.x;
  int b = t >> 6, j = t & 63;
  const float* gpb = gp + b*DIMC;
  const float* wr  = g1w + j*DIMC;
  float s = g1b[j];
  for(int c=0;c<DIMC;c++) s += gpb[c]*wr[c];
  h[b][j] = fmaxf(s, 0.f);
  __syncthreads();
  if (t < 8){
    int b2 = t >> 1, o = t & 1;
    float z = g2b[o];
    const float* w2 = g2w + o*64;
    for(int q=0;q<64;q++) z += w2[q]*h[b2][q];
    zz[b2][o] = z;
  }
  __syncthreads();
  if (t < 4){
    float z0 = zz[t][0], z1 = zz[t][1];
    float mm = fmaxf(z0,z1);
    float e0 = __expf(z0-mm), e1 = __expf(z1-mm);
    float inv = 1.0f/(e0+e1);
    cwaw[2*t]   = e0*inv;
    cwaw[2*t+1] = e1*inv;
  }
}

// ---------------- depthwise conv 3x3 + 5x5 + biases ----------------
__global__ __launch_bounds__(256) void dwconv_kernel(const bf* __restrict__ y,
    const float* __restrict__ w3, const float* __restrict__ b3,
    const float* __restrict__ w5, const float* __restrict__ b5,
    bf* __restrict__ out){
  int idx = blockIdx.x*256 + threadIdx.x;
  int wx = idx & 127;
  int rest = idx >> 7;
  int hy = rest & 127; rest >>= 7;
  int c  = rest & 255;
  int b  = rest >> 8;
  const bf* pl = y + ((size_t)b*DIMC + c)*HWs;
  const float* k3 = w3 + c*9;
  const float* k5 = w5 + c*25;
  float acc = b3[c] + b5[c];
  #pragma unroll
  for(int di=-2; di<=2; di++){
    int yy = hy + di;
    if((unsigned)yy >= (unsigned)HH) continue;
    const bf* prow = pl + yy*WW;
    #pragma unroll
    for(int dj=-2; dj<=2; dj++){
      int xx = wx + dj;
      if((unsigned)xx >= (unsigned)WW) continue;
      float v = b2f(prow[xx]);
      acc += v * k5[(di+2)*5 + (dj+2)];
      if (di>=-1 && di<=1 && dj>=-1 && dj<=1)
        acc += v * k3[(di+1)*3 + (dj+1)];
    }
  }
  out[idx] = f2b(acc);
}

// ---------------- grouped conv (2-2 per group, 3x3) fused with GLU ----------------
__global__ __launch_bounds__(256) void dwconv2_glu_kernel(const bf* __restrict__ p,
    const float* __restrict__ w, bf* __restrict__ m){
  int idx = blockIdx.x*256 + threadIdx.x;        // NB*HID*HWs
  int wx = idx & 127;
  int rest = idx >> 7;
  int hy = rest & 127; rest >>= 7;
  int o  = rest & 255;
  int b  = rest >> 8;
  int gi = o & ~1;
  const bf* p0 = p + ((size_t)b*C2 + gi)*HWs;
  const bf* p1 = p0 + HWs;
  const bf* p2 = p0 + (size_t)256*HWs;
  const bf* p3 = p2 + HWs;
  const float* k0 = w + o*18;
  const float* k1 = k0 + 9;
  const float* k2 = w + (o+256)*18;
  const float* k3 = k2 + 9;
  float a1 = 0.f, a2 = 0.f;
  #pragma unroll
  for(int di=-1; di<=1; di++){
    int yy = hy + di;
    if((unsigned)yy >= (unsigned)HH) continue;
    int roff = yy*WW;
    #pragma unroll
    for(int dj=-1; dj<=1; dj++){
      int xx = wx + dj;
      if((unsigned)xx >= (unsigned)WW) continue;
      int ki = (di+1)*3 + (dj+1);
      a1 += b2f(p0[roff+xx])*k0[ki] + b2f(p1[roff+xx])*k1[ki];
      a2 += b2f(p2[roff+xx])*k2[ki] + b2f(p3[roff+xx])*k3[ki];
    }
  }
  m[idx] = f2b(gelu_exact(a1)*a2);
}

// ---------------- bf16 MFMA GEMM (builtin MFMA; structure = R3's passing kernel) ----------------
template<typename TRES, typename TOUT>
__global__ __launch_bounds__(256, 2) void mfma_gemm(
    const u16* __restrict__ Wb, const bf* __restrict__ act,
    const float* __restrict__ bias, const TRES* __restrict__ resid,
    TOUT* __restrict__ out, int Oc)
{
  __shared__ u16 Bs[2][4096];
  int t  = threadIdx.x;
  int n0 = blockIdx.x * 128;
  int o0 = blockIdx.y * 128;
  int b  = n0 >> 14;
  int sp = n0 & (HWs-1);
  const u16* actu = (const u16*)act + (size_t)b*256*HWs + sp;

  int kp = t & 15;
  int ns = (t >> 4) << 3;
  int lane = t & 63;
  int wv = t >> 6;
  int wr = (wv >> 1) << 6;
  int wc = (wv & 1) << 6;
  int fr = lane & 15;
  int kg = lane >> 4;

  f32x4 acc[4][4] = {};

  auto stage = [&](int ks, int buf){
    const u16* r0 = actu + (size_t)(ks*32 + 2*kp)*HWs + ns;
    u32x4 u = *(const u32x4*)r0;
    u32x4 v = *(const u32x4*)(r0 + HWs);
    u32 w0=(u.x&0xffffu)|(v.x<<16), w1=(u.x>>16)|(v.x&0xffff0000u);
    u32 w2=(u.y&0xffffu)|(v.y<<16), w3=(u.y>>16)|(v.y&0xffff0000u);
    u32 w4=(u.z&0xffffu)|(v.z<<16), w5=(u.z>>16)|(v.z&0xffff0000u);
    u32 w6=(u.w&0xffffu)|(v.w<<16), w7=(u.w>>16)|(v.w&0xffff0000u);
    u16* bp = Bs[buf];
    int c0 = kp*2;
    *(u32*)&bp[(ns+0)*32+c0]=w0; *(u32*)&bp[(ns+1)*32+c0]=w1;
    *(u32*)&bp[(ns+2)*32+c0]=w2; *(u32*)&bp[(ns+3)*32+c0]=w3;
    *(u32*)&bp[(ns+4)*32+c0]=w4; *(u32*)&bp[(ns+5)*32+c0]=w5;
    *(u32*)&bp[(ns+6)*32+c0]=w6; *(u32*)&bp[(ns+7)*32+c0]=w7;
  };

  stage(0, 0);
  #pragma unroll
  for(int ks=0; ks<8; ++ks){
    int cur = ks & 1;
    __syncthreads();
    if (ks < 7) stage(ks+1, cur^1);
    bf16x8 af[4], bfr[4];
    #pragma unroll
    for(int i=0;i<4;i++)
      af[i] = *(const bf16x8*)(Wb + (size_t)(o0+wr+i*16+fr)*256 + ks*32 + kg*8);
    #pragma unroll
    for(int j=0;j<4;j++)
      bfr[j] = *(const bf16x8*)&Bs[cur][(wc + j*16 + fr)*32 + kg*8];
    #pragma unroll
    for(int i=0;i<4;i++)
      #pragma unroll
      for(int j=0;j<4;j++)
        acc[i][j] = __builtin_amdgcn_mfma_f32_16x16x32_bf16(af[i], bfr[j], acc[i][j], 0, 0, 0);
  }

  #pragma unroll
  for(int i=0;i<4;i++){
    #pragma unroll
    for(int reg=0;reg<4;reg++){
      int o = o0 + wr + i*16 + kg*4 + reg;
      size_t rowoff = ((size_t)b*Oc + o)*HWs + sp + wc + fr;
      float bia = bias ? bias[o] : 0.f;
      #pragma unroll
      for(int j=0;j<4;j++){
        float val = acc[i][j][reg] + bia;
        size_t pidx = rowoff + (size_t)(j*16);
        if (resid) val += ldf(resid + pidx);
        sto(out + pidx, val);
      }
    }
  }
}

// ---------------- per-slice logit scale ----------------
__global__ __launch_bounds__(256) void norm_kernel(const bf* __restrict__ qkv,
    const float* __restrict__ scale, float* __restrict__ lscale){
  int s = blockIdx.x;
  int b = s >> 8, ch = s & 255;
  const bf* qp = qkv + ((size_t)b*768 + ch)*HWs;
  const bf* kp = qp + (size_t)256*HWs;
  float sq=0.f, sk=0.f;
  for(int i=threadIdx.x;i<HWs;i+=256){
    float a = b2f(qp[i]); sq += a*a;
    float c = b2f(kp[i]); sk += c*c;
  }
  __shared__ float r1[256], r2[256];
  r1[threadIdx.x]=sq; r2[threadIdx.x]=sk;
  __syncthreads();
  for(int o=128;o>0;o>>=1){
    if(threadIdx.x<o){ r1[threadIdx.x]+=r1[threadIdx.x+o]; r2[threadIdx.x]+=r2[threadIdx.x+o]; }
    __syncthreads();
  }
  if(threadIdx.x==0){
    float nq = fmaxf(sqrtf(r1[0]), 1e-12f);
    float nk = fmaxf(sqrtf(r2[0]), 1e-12f);
    lscale[s] = scale[ch & 15] / (nq*nk);
  }
}

// byte offset into a [128 rows][128 bf16] LDS plane, 16B-chunk XOR swizzled
#define SWB(r,c2) ((r)*256 + ((c2) ^ (((r)&7)<<4)))

// ---------------- MFMA axial attention, one slice (b,nh,hd) per block ----------------
// DIR 0: S^T = K·Q^T, O^T via A=V^T,B=P.  DIR 1: S^T = K^T·Q'^T, O via A=P,B=V.
// Both write O to LDS as spatial [h][w]; MIX (dir1) fuses cw*conv + aw*(attnf+O).
template<int DIR, int MIX>
__global__ __launch_bounds__(256) void attn_mfma(const bf* __restrict__ qkv,
    const float* __restrict__ lscale, bf* __restrict__ attnf,
    const bf* __restrict__ conv, const float* __restrict__ cwaw){
  __shared__ u16 LB0[16384];   // 32 KB
  __shared__ u16 LB1[16384];   // 32 KB
  int s  = blockIdx.x;
  int b  = s >> 8;
  int ch = s & 255;
  const u16* qp = (const u16*)qkv + ((size_t)b*768 + ch)*HWs;
  const u16* kp = qp + (size_t)256*HWs;
  const u16* vp = qp + (size_t)512*HWs;
  int t = threadIdx.x;
  float ls = lscale[s];

  int lane = t & 63, wvi = t >> 6;
  int fr = lane & 15, kg = lane >> 4;
  int nb = wvi << 5;                       // wave's 32-col base
  int rr = t >> 1, hb = (t & 1) << 7;      // copy rows / half (bytes)

  // natural stage: LDS[r][c] = src[r][c]
  auto stage_nat = [&](const u16* src, u16* dst){
    #pragma unroll
    for(int i=0;i<8;i++){
      int c2 = hb + i*16;
      u32x4 v = *(const u32x4*)((const char*)src + rr*256 + c2);
      *(u32x4*)((char*)dst + SWB(rr, c2)) = v;
    }
  };
  // transposed stage: LDS[c][r] = src[r][c]  (pack row-pairs into u32)
  auto stage_tr = [&](const u16* src, u16* dst){
    int kp2 = (t & 15)*2, cs = (t >> 4) << 3;
    #pragma unroll
    for(int base=0;base<128;base+=32){
      int sr = base + kp2;
      u32x4 u = *(const u32x4*)(src + sr*128 + cs);
      u32x4 v = *(const u32x4*)(src + (sr+1)*128 + cs);
      #pragma unroll
      for(int j=0;j<8;j++){
        u32 uw = ((const u32*)&u)[j>>1];
        u32 vw = ((const u32*)&v)[j>>1];
        u32 wv = (j&1) ? ((uw>>16) | (vw & 0xffff0000u))
                       : ((uw & 0xffffu) | (vw<<16));
        *(u32*)((char*)dst + SWB(cs+j, sr*2)) = wv;
      }
    }
  };

  f32x4 acc[8][2];
  const f32x4 vzero = {};

  // one K-sweep MFMA: acc[mt][nt] += A(afsrc rows mt*16+fr) x B^T(bfsrc rows nb+nt*16+fr)
  auto mmloop = [&](const u16* afsrc, const u16* bfsrc){
    #pragma unroll
    for(int kk=0;kk<128;kk+=32){
      int kb2 = kk*2 + kg*16;
      bf16x8 b0 = *(const bf16x8*)((const char*)bfsrc + SWB(nb+fr,    kb2));
      bf16x8 b1 = *(const bf16x8*)((const char*)bfsrc + SWB(nb+16+fr, kb2));
      #pragma unroll
      for(int mt=0;mt<8;mt++){
        bf16x8 a0 = *(const bf16x8*)((const char*)afsrc + SWB(mt*16+fr, kb2));
        acc[mt][0] = __builtin_amdgcn_mfma_f32_16x16x32_bf16(a0, b0, acc[mt][0], 0, 0, 0);
        acc[mt][1] = __builtin_amdgcn_mfma_f32_16x16x32_bf16(a0, b1, acc[mt][1], 0, 0, 0);
      }
    }
  };

  // write acc (C layout) to dst as [n][m] bf16, reg-pair packed
  auto writeCT = [&](u16* dst){
    #pragma unroll
    for(int nt=0;nt<2;nt++){
      int n = nb + nt*16 + fr;
      #pragma unroll
      for(int mt=0;mt<8;mt++){
        #pragma unroll
        for(int pr=0;pr<2;pr++){
          u32 wv = pack2(acc[mt][nt][pr*2], acc[mt][nt][pr*2+1]);
          int z2 = (mt*16 + kg*4 + pr*2)*2;
          *(u32*)((char*)dst + SWB(n, z2)) = wv;
        }
      }
    }
  };

  // phase 1: stage S-operands
  if (DIR==0){ stage_nat(kp, LB0); stage_nat(qp, LB1); }
  else       { stage_tr (kp, LB0); stage_tr (qp, LB1); }
  __syncthreads();

  // phase 2: S^T
  #pragma unroll
  for(int mt=0;mt<8;mt++){ acc[mt][0]=vzero; acc[mt][1]=vzero; }
  mmloop(LB0, LB1);

  // phase 3: softmax over rows z (in-lane 32 + shfl 16/32)
  #pragma unroll
  for(int nt=0;nt<2;nt++){
    float mx = -1e30f;
    #pragma unroll
    for(int mt=0;mt<8;mt++)
      #pragma unroll
      for(int rg=0;rg<4;rg++){
        acc[mt][nt][rg] *= ls;
        mx = fmaxf(mx, acc[mt][nt][rg]);
      }
    mx = fmaxf(mx, __shfl_xor(mx,16));
    mx = fmaxf(mx, __shfl_xor(mx,32));
    float sm = 0.f;
    #pragma unroll
    for(int mt=0;mt<8;mt++)
      #pragma unroll
      for(int rg=0;rg<4;rg++){
        float e = __expf(acc[mt][nt][rg]-mx);
        acc[mt][nt][rg] = e; sm += e;
      }
    sm += __shfl_xor(sm,16);
    sm += __shfl_xor(sm,32);
    float inv = 1.0f/sm;
    #pragma unroll
    for(int mt=0;mt<8;mt++)
      #pragma unroll
      for(int rg=0;rg<4;rg++)
        acc[mt][nt][rg] *= inv;
  }
  __syncthreads();                 // everyone done reading LB0/LB1

  // phase 4: P -> LB0, V -> LB1
  writeCT(LB0);
  if (DIR==0) stage_tr(vp, LB1); else stage_nat(vp, LB1);
  __syncthreads();

  // phase 5: O (dir0: A=V^T,B=P -> O^T ; dir1: A=P,B=V -> O)
  #pragma unroll
  for(int mt=0;mt<8;mt++){ acc[mt][0]=vzero; acc[mt][1]=vzero; }
  if (DIR==0) mmloop(LB1, LB0);
  else        mmloop(LB0, LB1);
  __syncthreads();                 // done reading P/V

  // phase 6: O -> LB0 as spatial [h][w]
  writeCT(LB0);
  __syncthreads();

  // phase 7: coalesced copy-out (+ MIX fusion)
  bf* op = attnf + ((size_t)b*DIMC + ch)*HWs;
  if (MIX){
    float cw = cwaw[2*b], aw = cwaw[2*b+1];
    const u16* cp = (const u16*)conv + ((size_t)b*DIMC + ch)*HWs;
    #pragma unroll
    for(int i=0;i<8;i++){
      int c2 = hb + i*16;
      u32x4 ov = *(const u32x4*)((char*)LB0 + SWB(rr, c2));
      const u16* ap = (const u16*)op + rr*128 + c2/2;
      u32x4 av = *(const u32x4*)ap;
      u32x4 cv = *(const u32x4*)(cp + rr*128 + c2/2);
      u32x4 res;
      #pragma unroll
      for(int q=0;q<4;q++){
        float o0,o1,a0,a1,c0,c1;
        unpack2(((u32*)&ov)[q], o0, o1);
        unpack2(((u32*)&av)[q], a0, a1);
        unpack2(((u32*)&cv)[q], c0, c1);
        ((u32*)&res)[q] = pack2(cw*c0 + aw*(a0+o0), cw*c1 + aw*(a1+o1));
      }
      *(u32x4*)((u16*)op + rr*128 + c2/2) = res;
    }
  } else {
    #pragma unroll
    for(int i=0;i<8;i++){
      int c2 = hb + i*16;
      u32x4 ov = *(const u32x4*)((char*)LB0 + SWB(rr, c2));
      *(u32x4*)((u16*)op + rr*128 + c2/2) = ov;
    }
  }
}

// ---------------- launch ----------------
extern "C" void kernel_launch(void* const* d_in, const int* in_sizes, int n_in,
                              void* d_out, int out_size, void* d_ws, size_t ws_size,
                              hipStream_t stream){
  (void)in_sizes; (void)n_in; (void)out_size; (void)ws_size;
  const float* x       = (const float*)d_in[0];
  const float* ln1_w   = (const float*)d_in[1];
  const float* ln1_b   = (const float*)d_in[2];
  const float* conv3_w = (const float*)d_in[3];
  const float* conv3_b = (const float*)d_in[4];
  const float* conv5_w = (const float*)d_in[5];
  const float* conv5_b = (const float*)d_in[6];
  const float* qkv_w   = (const float*)d_in[7];
  const float* scale   = (const float*)d_in[8];
  const float* g1_w    = (const float*)d_in[9];
  const float* g1_b    = (const float*)d_in[10];
  const float* g2_w    = (const float*)d_in[11];
  const float* g2_b    = (const float*)d_in[12];
  const float* proj_w  = (const float*)d_in[13];
  const float* proj_b  = (const float*)d_in[14];
  const float* ln2_w   = (const float*)d_in[15];
  const float* ln2_b   = (const float*)d_in[16];
  const float* pin_w   = (const float*)d_in[17];
  const float* dw_w    = (const float*)d_in[18];
  const float* pout_w  = (const float*)d_in[19];
  float* out = (float*)d_out;
  char* wsb  = (char*)d_ws;

  const size_t MB = 1024*1024;
  bf* y    = (bf*)(wsb +   0*MB);
  bf* conv = (bf*)(wsb +  32*MB);
  bf* qkv  = (bf*)(wsb +  64*MB);
  bf* attnf= (bf*)(wsb +   0*MB);
  bf* xnew = (bf*)(wsb +  64*MB);
  bf* y2   = (bf*)(wsb +  96*MB);
  bf* p    = (bf*)(wsb +   0*MB);
  bf* m    = (bf*)(wsb +  96*MB);
  u16* Wqkv  = (u16*)(wsb + 160*MB);
  u16* Wproj = Wqkv + 196608;
  u16* Wpin  = Wproj + 65536;
  u16* Wpout = Wpin + 131072;
  float* gp     = (float*)(Wpout + 65536);
  float* cwaw   = gp + 1024;
  float* lscale = cwaw + 16;

  cvt_kernel<<<768,256,0,stream>>>(qkv_w,  Wqkv, 196608);
  cvt_kernel<<<256,256,0,stream>>>(proj_w, Wproj, 65536);
  cvt_kernel<<<512,256,0,stream>>>(pin_w,  Wpin, 131072);
  cvt_kernel<<<256,256,0,stream>>>(pout_w, Wpout, 65536);

  ln_kernel<float><<<256,256,0,stream>>>(x, ln1_w, ln1_b, y);
  gp_kernel<<<1024,256,0,stream>>>(y, gp);
  gate_kernel<<<1,256,0,stream>>>(gp, g1_w, g1_b, g2_w, g2_b, cwaw);
  dwconv_kernel<<<65536,256,0,stream>>>(y, conv3_w, conv3_b, conv5_w, conv5_b, conv);
  mfma_gemm<float,bf><<<dim3(512,6),256,0,stream>>>(Wqkv, y, nullptr,
                                        (const float*)nullptr, qkv, 768);
  norm_kernel<<<1024,256,0,stream>>>(qkv, scale, lscale);
  attn_mfma<0,0><<<1024,256,0,stream>>>(qkv, lscale, attnf, nullptr, nullptr);
  attn_mfma<1,1><<<1024,256,0,stream>>>(qkv, lscale, attnf, conv, cwaw);
  mfma_gemm<float,bf><<<dim3(512,2),256,0,stream>>>(Wproj, attnf, proj_b, x, xnew, 256);
  ln_kernel<bf><<<256,256,0,stream>>>(xnew, ln2_w, ln2_b, y2);
  mfma_gemm<float,bf><<<dim3(512,4),256,0,stream>>>(Wpin, y2, nullptr,
                                        (const float*)nullptr, p, 512);
  dwconv2_glu_kernel<<<65536,256,0,stream>>>(p, dw_w, m);
  mfma_gemm<bf,float><<<dim3(512,2),256,0,stream>>>(Wpout, m, nullptr, xnew, out, 256);
}

// Round 6
// 571.214 us; speedup vs baseline: 2.8076x; 1.3894x over previous
//
#include <hip/hip_runtime.h>
#include <hip/hip_bf16.h>
#include <math.h>

#define DIMC 256
#define NB   4
#define HH   128
#define WW   128
#define HWs  16384
#define HID  256
#define C2   512
#define EPSf 1e-5f

typedef __hip_bfloat16 bf;
typedef unsigned short u16;
typedef unsigned int   u32;
typedef float f32x4  __attribute__((ext_vector_type(4)));
typedef u32   u32x4  __attribute__((ext_vector_type(4)));
typedef short bf16x8 __attribute__((ext_vector_type(8)));

__device__ __forceinline__ float b2f(bf v){ return __bfloat162float(v); }
__device__ __forceinline__ bf    f2b(float v){ return __float2bfloat16(v); }
__device__ __forceinline__ float ldf(const float* p){ return *p; }
__device__ __forceinline__ float ldf(const bf* p){ return __bfloat162float(*p); }
__device__ __forceinline__ void  sto(float* p, float v){ *p = v; }
__device__ __forceinline__ void  sto(bf* p, float v){ *p = f2b(v); }
__device__ __forceinline__ void unpack2(u32 u, float& a, float& b){
  union{u32 x; float f;} lo, hi;
  lo.x = u << 16; hi.x = u & 0xffff0000u;
  a = lo.f; b = hi.f;
}
__device__ __forceinline__ u32 pack2(float a, float b){
  bf h0 = f2b(a), h1 = f2b(b);
  return (u32)*(u16*)&h0 | ((u32)*(u16*)&h1 << 16);
}
__device__ __forceinline__ void unp4(uint2 u, float* d){
  unpack2(u.x, d[0], d[1]); unpack2(u.y, d[2], d[3]);
}

__device__ __forceinline__ float gelu_exact(float v){
  return 0.5f*v*(1.0f + erff(v*0.70710678118654752f));
}

// ---------------- weight fp32 -> bf16 convert ----------------
__global__ __launch_bounds__(256) void cvt_kernel(const float* __restrict__ s,
    u16* __restrict__ d, int n){
  int i = blockIdx.x*256 + threadIdx.x;
  if (i < n){ bf h = f2b(s[i]); d[i] = *(u16*)&h; }
}

// ---------------- LayerNorm over channel dim (per pixel), bf16 out ----------------
template<typename TI>
__global__ __launch_bounds__(256) void ln_kernel(const TI* __restrict__ x,
    const float* __restrict__ w, const float* __restrict__ bb, bf* __restrict__ y){
  int p = blockIdx.x*256 + threadIdx.x;
  int b  = p >> 14;
  int sp = p & (HWs-1);
  const TI* xb = x + (size_t)b*DIMC*HWs + sp;
  float s = 0.f, s2 = 0.f;
  for(int c=0;c<DIMC;c++){ float v = ldf(xb + (size_t)c*HWs); s += v; s2 += v*v; }
  float mu   = s * (1.0f/DIMC);
  float var  = s2 * (1.0f/DIMC) - mu*mu;
  float rinv = rsqrtf(var + EPSf);
  bf* yb = y + (size_t)b*DIMC*HWs + sp;
  for(int c=0;c<DIMC;c++){
    float v = ldf(xb + (size_t)c*HWs);
    yb[(size_t)c*HWs] = f2b((v - mu)*rinv*w[c] + bb[c]);
  }
}

// ---------------- global average pool per (b,c) ----------------
__global__ __launch_bounds__(256) void gp_kernel(const bf* __restrict__ y, float* __restrict__ gp){
  int bc = blockIdx.x;
  const bf* pl = y + (size_t)bc*HWs;
  float s = 0.f;
  for(int i=threadIdx.x;i<HWs;i+=256) s += b2f(pl[i]);
  __shared__ float red[256];
  red[threadIdx.x] = s; __syncthreads();
  for(int o=128;o>0;o>>=1){
    if(threadIdx.x<o) red[threadIdx.x] += red[threadIdx.x+o];
    __syncthreads();
  }
  if(threadIdx.x==0) gp[bc] = red[0]*(1.0f/HWs);
}

// ---------------- gating MLP (tiny) ----------------
__global__ __launch_bounds__(256) void gate_kernel(const float* __restrict__ gp,
    const float* __restrict__ g1w, const float* __restrict__ g1b,
    const float* __restrict__ g2w, const float* __restrict__ g2b,
    float* __restrict__ cwaw){
  __shared__ float h[NB][64];
  __shared__ float zz[NB][2];
  int t = threadIdx.x;
  int b = t >> 6, j = t & 63;
  const float* gpb = gp + b*DIMC;
  const float* wr  = g1w + j*DIMC;
  float s = g1b[j];
  for(int c=0;c<DIMC;c++) s += gpb[c]*wr[c];
  h[b][j] = fmaxf(s, 0.f);
  __syncthreads();
  if (t < 8){
    int b2 = t >> 1, o = t & 1;
    float z = g2b[o];
    const float* w2 = g2w + o*64;
    for(int q=0;q<64;q++) z += w2[q]*h[b2][q];
    zz[b2][o] = z;
  }
  __syncthreads();
  if (t < 4){
    float z0 = zz[t][0], z1 = zz[t][1];
    float mm = fmaxf(z0,z1);
    float e0 = __expf(z0-mm), e1 = __expf(z1-mm);
    float inv = 1.0f/(e0+e1);
    cwaw[2*t]   = e0*inv;
    cwaw[2*t+1] = e1*inv;
  }
}

// ---------------- depthwise conv 3x3 + 5x5, register-tiled ----------------
// thread = (b, c, row hy, 8-wide strip sx); vector uint2 window loads
__global__ __launch_bounds__(256) void dwconv_kernel(const bf* __restrict__ y,
    const float* __restrict__ w3, const float* __restrict__ b3,
    const float* __restrict__ w5, const float* __restrict__ b5,
    bf* __restrict__ out){
  int idx = blockIdx.x*256 + threadIdx.x;        // 4*256*128*16
  int sx = idx & 15;
  int hy = (idx >> 4) & 127;
  int c  = (idx >> 11) & 255;
  int b  = idx >> 19;
  int x0 = sx << 3;
  const u16* pl = (const u16*)y + ((size_t)(b*DIMC + c))*HWs;

  float k5v[25], k3v[9];
  #pragma unroll
  for(int i=0;i<25;i++) k5v[i] = w5[c*25+i];
  #pragma unroll
  for(int i=0;i<9;i++)  k3v[i] = w3[c*9+i];

  float acc[8];
  float bia = b3[c] + b5[c];
  #pragma unroll
  for(int j=0;j<8;j++) acc[j] = bia;

  #pragma unroll
  for(int di=-2; di<=2; di++){
    int yy = hy + di;
    float row[16];
    if ((unsigned)yy < 128u){
      const u16* rp = pl + yy*WW;
      uint2 z; z.x = 0u; z.y = 0u;
      uint2 c0 = (x0 > 0)   ? *(const uint2*)(rp + x0 - 4) : z;
      uint2 c1 = *(const uint2*)(rp + x0);
      uint2 c2 = *(const uint2*)(rp + x0 + 4);
      uint2 c3 = (x0 < 120) ? *(const uint2*)(rp + x0 + 8) : z;
      unp4(c0, row); unp4(c1, row+4); unp4(c2, row+8); unp4(c3, row+12);
    } else {
      #pragma unroll
      for(int j=0;j<16;j++) row[j] = 0.f;
    }
    #pragma unroll
    for(int dj=-2; dj<=2; dj++){
      float w = k5v[(di+2)*5 + (dj+2)];
      if (di>=-1 && di<=1 && dj>=-1 && dj<=1)
        w += k3v[(di+1)*3 + (dj+1)];
      #pragma unroll
      for(int j=0;j<8;j++) acc[j] += row[4+j+dj]*w;
    }
  }
  u32x4 res;
  #pragma unroll
  for(int q=0;q<4;q++) ((u32*)&res)[q] = pack2(acc[2*q], acc[2*q+1]);
  *(u32x4*)((u16*)out + ((size_t)(b*DIMC + c))*HWs + hy*WW + x0) = res;
}

// ---------------- grouped conv (2-2 per group, 3x3) + GLU, register-tiled ----------------
__global__ __launch_bounds__(256) void dwconv2_glu_kernel(const bf* __restrict__ p,
    const float* __restrict__ w, bf* __restrict__ m){
  int idx = blockIdx.x*256 + threadIdx.x;        // 4*256*128*16
  int sx = idx & 15;
  int hy = (idx >> 4) & 127;
  int o  = (idx >> 11) & 255;
  int b  = idx >> 19;
  int x0 = sx << 3;
  int gi = o & ~1;
  const u16* p0 = (const u16*)p + ((size_t)b*C2 + gi)*HWs;
  const u16* p1 = p0 + HWs;
  const u16* p2 = p0 + (size_t)256*HWs;
  const u16* p3 = p2 + HWs;

  float K0[9], K1[9], K2[9], K3[9];
  #pragma unroll
  for(int i=0;i<9;i++){
    K0[i] = w[o*18 + i];
    K1[i] = w[o*18 + 9 + i];
    K2[i] = w[(o+256)*18 + i];
    K3[i] = w[(o+256)*18 + 9 + i];
  }

  float a1[8] = {}, a2[8] = {};
  #pragma unroll
  for(int di=-1; di<=1; di++){
    int yy = hy + di;
    if ((unsigned)yy >= 128u) continue;
    int roff = yy*WW;
    float r0[16], r1[16], r2[16], r3[16];
    uint2 z; z.x = 0u; z.y = 0u;
    bool lo = (x0 > 0), hi = (x0 < 120);
    {
      const u16* rp = p0 + roff;
      uint2 c0 = lo ? *(const uint2*)(rp + x0 - 4) : z;
      uint2 c1 = *(const uint2*)(rp + x0);
      uint2 c2 = *(const uint2*)(rp + x0 + 4);
      uint2 c3 = hi ? *(const uint2*)(rp + x0 + 8) : z;
      unp4(c0, r0); unp4(c1, r0+4); unp4(c2, r0+8); unp4(c3, r0+12);
    }
    {
      const u16* rp = p1 + roff;
      uint2 c0 = lo ? *(const uint2*)(rp + x0 - 4) : z;
      uint2 c1 = *(const uint2*)(rp + x0);
      uint2 c2 = *(const uint2*)(rp + x0 + 4);
      uint2 c3 = hi ? *(const uint2*)(rp + x0 + 8) : z;
      unp4(c0, r1); unp4(c1, r1+4); unp4(c2, r1+8); unp4(c3, r1+12);
    }
    {
      const u16* rp = p2 + roff;
      uint2 c0 = lo ? *(const uint2*)(rp + x0 - 4) : z;
      uint2 c1 = *(const uint2*)(rp + x0);
      uint2 c2 = *(const uint2*)(rp + x0 + 4);
      uint2 c3 = hi ? *(const uint2*)(rp + x0 + 8) : z;
      unp4(c0, r2); unp4(c1, r2+4); unp4(c2, r2+8); unp4(c3, r2+12);
    }
    {
      const u16* rp = p3 + roff;
      uint2 c0 = lo ? *(const uint2*)(rp + x0 - 4) : z;
      uint2 c1 = *(const uint2*)(rp + x0);
      uint2 c2 = *(const uint2*)(rp + x0 + 4);
      uint2 c3 = hi ? *(const uint2*)(rp + x0 + 8) : z;
      unp4(c0, r3); unp4(c1, r3+4); unp4(c2, r3+8); unp4(c3, r3+12);
    }
    #pragma unroll
    for(int dj=-1; dj<=1; dj++){
      int ki = (di+1)*3 + (dj+1);
      float w0 = K0[ki], w1 = K1[ki], w2 = K2[ki], w3v = K3[ki];
      #pragma unroll
      for(int j=0;j<8;j++){
        int ii = 4+j+dj;
        a1[j] += r0[ii]*w0 + r1[ii]*w1;
        a2[j] += r2[ii]*w2 + r3[ii]*w3v;
      }
    }
  }
  u32x4 res;
  #pragma unroll
  for(int q=0;q<4;q++)
    ((u32*)&res)[q] = pack2(gelu_exact(a1[2*q])*a2[2*q],
                            gelu_exact(a1[2*q+1])*a2[2*q+1]);
  *(u32x4*)((u16*)m + ((size_t)(b*DIMC + o))*HWs + hy*WW + x0) = res;
}

// ---------------- bf16 MFMA GEMM (unchanged, passed R5) ----------------
template<typename TRES, typename TOUT>
__global__ __launch_bounds__(256, 2) void mfma_gemm(
    const u16* __restrict__ Wb, const bf* __restrict__ act,
    const float* __restrict__ bias, const TRES* __restrict__ resid,
    TOUT* __restrict__ out, int Oc)
{
  __shared__ u16 Bs[2][4096];
  int t  = threadIdx.x;
  int n0 = blockIdx.x * 128;
  int o0 = blockIdx.y * 128;
  int b  = n0 >> 14;
  int sp = n0 & (HWs-1);
  const u16* actu = (const u16*)act + (size_t)b*256*HWs + sp;

  int kp = t & 15;
  int ns = (t >> 4) << 3;
  int lane = t & 63;
  int wv = t >> 6;
  int wr = (wv >> 1) << 6;
  int wc = (wv & 1) << 6;
  int fr = lane & 15;
  int kg = lane >> 4;

  f32x4 acc[4][4] = {};

  auto stage = [&](int ks, int buf){
    const u16* r0 = actu + (size_t)(ks*32 + 2*kp)*HWs + ns;
    u32x4 u = *(const u32x4*)r0;
    u32x4 v = *(const u32x4*)(r0 + HWs);
    u32 w0=(u.x&0xffffu)|(v.x<<16), w1=(u.x>>16)|(v.x&0xffff0000u);
    u32 w2=(u.y&0xffffu)|(v.y<<16), w3=(u.y>>16)|(v.y&0xffff0000u);
    u32 w4=(u.z&0xffffu)|(v.z<<16), w5=(u.z>>16)|(v.z&0xffff0000u);
    u32 w6=(u.w&0xffffu)|(v.w<<16), w7=(u.w>>16)|(v.w&0xffff0000u);
    u16* bp = Bs[buf];
    int c0 = kp*2;
    *(u32*)&bp[(ns+0)*32+c0]=w0; *(u32*)&bp[(ns+1)*32+c0]=w1;
    *(u32*)&bp[(ns+2)*32+c0]=w2; *(u32*)&bp[(ns+3)*32+c0]=w3;
    *(u32*)&bp[(ns+4)*32+c0]=w4; *(u32*)&bp[(ns+5)*32+c0]=w5;
    *(u32*)&bp[(ns+6)*32+c0]=w6; *(u32*)&bp[(ns+7)*32+c0]=w7;
  };

  stage(0, 0);
  #pragma unroll
  for(int ks=0; ks<8; ++ks){
    int cur = ks & 1;
    __syncthreads();
    if (ks < 7) stage(ks+1, cur^1);
    bf16x8 af[4], bfr[4];
    #pragma unroll
    for(int i=0;i<4;i++)
      af[i] = *(const bf16x8*)(Wb + (size_t)(o0+wr+i*16+fr)*256 + ks*32 + kg*8);
    #pragma unroll
    for(int j=0;j<4;j++)
      bfr[j] = *(const bf16x8*)&Bs[cur][(wc + j*16 + fr)*32 + kg*8];
    #pragma unroll
    for(int i=0;i<4;i++)
      #pragma unroll
      for(int j=0;j<4;j++)
        acc[i][j] = __builtin_amdgcn_mfma_f32_16x16x32_bf16(af[i], bfr[j], acc[i][j], 0, 0, 0);
  }

  #pragma unroll
  for(int i=0;i<4;i++){
    #pragma unroll
    for(int reg=0;reg<4;reg++){
      int o = o0 + wr + i*16 + kg*4 + reg;
      size_t rowoff = ((size_t)b*Oc + o)*HWs + sp + wc + fr;
      float bia = bias ? bias[o] : 0.f;
      #pragma unroll
      for(int j=0;j<4;j++){
        float val = acc[i][j][reg] + bia;
        size_t pidx = rowoff + (size_t)(j*16);
        if (resid) val += ldf(resid + pidx);
        sto(out + pidx, val);
      }
    }
  }
}

// ---------------- per-slice logit scale ----------------
__global__ __launch_bounds__(256) void norm_kernel(const bf* __restrict__ qkv,
    const float* __restrict__ scale, float* __restrict__ lscale){
  int s = blockIdx.x;
  int b = s >> 8, ch = s & 255;
  const bf* qp = qkv + ((size_t)b*768 + ch)*HWs;
  const bf* kp = qp + (size_t)256*HWs;
  float sq=0.f, sk=0.f;
  for(int i=threadIdx.x;i<HWs;i+=256){
    float a = b2f(qp[i]); sq += a*a;
    float c = b2f(kp[i]); sk += c*c;
  }
  __shared__ float r1[256], r2[256];
  r1[threadIdx.x]=sq; r2[threadIdx.x]=sk;
  __syncthreads();
  for(int o=128;o>0;o>>=1){
    if(threadIdx.x<o){ r1[threadIdx.x]+=r1[threadIdx.x+o]; r2[threadIdx.x]+=r2[threadIdx.x+o]; }
    __syncthreads();
  }
  if(threadIdx.x==0){
    float nq = fmaxf(sqrtf(r1[0]), 1e-12f);
    float nk = fmaxf(sqrtf(r2[0]), 1e-12f);
    lscale[s] = scale[ch & 15] / (nq*nk);
  }
}

// byte offset into a [128 rows][128 bf16] LDS plane, 16B-chunk XOR swizzled
#define SWB(r,c2) ((r)*256 + ((c2) ^ (((r)&7)<<4)))

// ---------------- MFMA axial attention (unchanged, passed R5) ----------------
template<int DIR, int MIX>
__global__ __launch_bounds__(256) void attn_mfma(const bf* __restrict__ qkv,
    const float* __restrict__ lscale, bf* __restrict__ attnf,
    const bf* __restrict__ conv, const float* __restrict__ cwaw){
  __shared__ u16 LB0[16384];
  __shared__ u16 LB1[16384];
  int s  = blockIdx.x;
  int b  = s >> 8;
  int ch = s & 255;
  const u16* qp = (const u16*)qkv + ((size_t)b*768 + ch)*HWs;
  const u16* kp = qp + (size_t)256*HWs;
  const u16* vp = qp + (size_t)512*HWs;
  int t = threadIdx.x;
  float ls = lscale[s];

  int lane = t & 63, wvi = t >> 6;
  int fr = lane & 15, kg = lane >> 4;
  int nb = wvi << 5;
  int rr = t >> 1, hb = (t & 1) << 7;

  auto stage_nat = [&](const u16* src, u16* dst){
    #pragma unroll
    for(int i=0;i<8;i++){
      int c2 = hb + i*16;
      u32x4 v = *(const u32x4*)((const char*)src + rr*256 + c2);
      *(u32x4*)((char*)dst + SWB(rr, c2)) = v;
    }
  };
  auto stage_tr = [&](const u16* src, u16* dst){
    int kp2 = (t & 15)*2, cs = (t >> 4) << 3;
    #pragma unroll
    for(int base=0;base<128;base+=32){
      int sr = base + kp2;
      u32x4 u = *(const u32x4*)(src + sr*128 + cs);
      u32x4 v = *(const u32x4*)(src + (sr+1)*128 + cs);
      #pragma unroll
      for(int j=0;j<8;j++){
        u32 uw = ((const u32*)&u)[j>>1];
        u32 vw = ((const u32*)&v)[j>>1];
        u32 wv = (j&1) ? ((uw>>16) | (vw & 0xffff0000u))
                       : ((uw & 0xffffu) | (vw<<16));
        *(u32*)((char*)dst + SWB(cs+j, sr*2)) = wv;
      }
    }
  };

  f32x4 acc[8][2];
  const f32x4 vzero = {};

  auto mmloop = [&](const u16* afsrc, const u16* bfsrc){
    #pragma unroll
    for(int kk=0;kk<128;kk+=32){
      int kb2 = kk*2 + kg*16;
      bf16x8 b0 = *(const bf16x8*)((const char*)bfsrc + SWB(nb+fr,    kb2));
      bf16x8 b1 = *(const bf16x8*)((const char*)bfsrc + SWB(nb+16+fr, kb2));
      #pragma unroll
      for(int mt=0;mt<8;mt++){
        bf16x8 a0 = *(const bf16x8*)((const char*)afsrc + SWB(mt*16+fr, kb2));
        acc[mt][0] = __builtin_amdgcn_mfma_f32_16x16x32_bf16(a0, b0, acc[mt][0], 0, 0, 0);
        acc[mt][1] = __builtin_amdgcn_mfma_f32_16x16x32_bf16(a0, b1, acc[mt][1], 0, 0, 0);
      }
    }
  };

  auto writeCT = [&](u16* dst){
    #pragma unroll
    for(int nt=0;nt<2;nt++){
      int n = nb + nt*16 + fr;
      #pragma unroll
      for(int mt=0;mt<8;mt++){
        #pragma unroll
        for(int pr=0;pr<2;pr++){
          u32 wv = pack2(acc[mt][nt][pr*2], acc[mt][nt][pr*2+1]);
          int z2 = (mt*16 + kg*4 + pr*2)*2;
          *(u32*)((char*)dst + SWB(n, z2)) = wv;
        }
      }
    }
  };

  if (DIR==0){ stage_nat(kp, LB0); stage_nat(qp, LB1); }
  else       { stage_tr (kp, LB0); stage_tr (qp, LB1); }
  __syncthreads();

  #pragma unroll
  for(int mt=0;mt<8;mt++){ acc[mt][0]=vzero; acc[mt][1]=vzero; }
  mmloop(LB0, LB1);

  #pragma unroll
  for(int nt=0;nt<2;nt++){
    float mx = -1e30f;
    #pragma unroll
    for(int mt=0;mt<8;mt++)
      #pragma unroll
      for(int rg=0;rg<4;rg++){
        acc[mt][nt][rg] *= ls;
        mx = fmaxf(mx, acc[mt][nt][rg]);
      }
    mx = fmaxf(mx, __shfl_xor(mx,16));
    mx = fmaxf(mx, __shfl_xor(mx,32));
    float sm = 0.f;
    #pragma unroll
    for(int mt=0;mt<8;mt++)
      #pragma unroll
      for(int rg=0;rg<4;rg++){
        float e = __expf(acc[mt][nt][rg]-mx);
        acc[mt][nt][rg] = e; sm += e;
      }
    sm += __shfl_xor(sm,16);
    sm += __shfl_xor(sm,32);
    float inv = 1.0f/sm;
    #pragma unroll
    for(int mt=0;mt<8;mt++)
      #pragma unroll
      for(int rg=0;rg<4;rg++)
        acc[mt][nt][rg] *= inv;
  }
  __syncthreads();

  writeCT(LB0);
  if (DIR==0) stage_tr(vp, LB1); else stage_nat(vp, LB1);
  __syncthreads();

  #pragma unroll
  for(int mt=0;mt<8;mt++){ acc[mt][0]=vzero; acc[mt][1]=vzero; }
  if (DIR==0) mmloop(LB1, LB0);
  else        mmloop(LB0, LB1);
  __syncthreads();

  writeCT(LB0);
  __syncthreads();

  bf* op = attnf + ((size_t)b*DIMC + ch)*HWs;
  if (MIX){
    float cw = cwaw[2*b], aw = cwaw[2*b+1];
    const u16* cp = (const u16*)conv + ((size_t)b*DIMC + ch)*HWs;
    #pragma unroll
    for(int i=0;i<8;i++){
      int c2 = hb + i*16;
      u32x4 ov = *(const u32x4*)((char*)LB0 + SWB(rr, c2));
      const u16* ap = (const u16*)op + rr*128 + c2/2;
      u32x4 av = *(const u32x4*)ap;
      u32x4 cv = *(const u32x4*)(cp + rr*128 + c2/2);
      u32x4 res;
      #pragma unroll
      for(int q=0;q<4;q++){
        float o0,o1,a0,a1,c0,c1;
        unpack2(((u32*)&ov)[q], o0, o1);
        unpack2(((u32*)&av)[q], a0, a1);
        unpack2(((u32*)&cv)[q], c0, c1);
        ((u32*)&res)[q] = pack2(cw*c0 + aw*(a0+o0), cw*c1 + aw*(a1+o1));
      }
      *(u32x4*)((u16*)op + rr*128 + c2/2) = res;
    }
  } else {
    #pragma unroll
    for(int i=0;i<8;i++){
      int c2 = hb + i*16;
      u32x4 ov = *(const u32x4*)((char*)LB0 + SWB(rr, c2));
      *(u32x4*)((u16*)op + rr*128 + c2/2) = ov;
    }
  }
}

// ---------------- launch ----------------
extern "C" void kernel_launch(void* const* d_in, const int* in_sizes, int n_in,
                              void* d_out, int out_size, void* d_ws, size_t ws_size,
                              hipStream_t stream){
  (void)in_sizes; (void)n_in; (void)out_size; (void)ws_size;
  const float* x       = (const float*)d_in[0];
  const float* ln1_w   = (const float*)d_in[1];
  const float* ln1_b   = (const float*)d_in[2];
  const float* conv3_w = (const float*)d_in[3];
  const float* conv3_b = (const float*)d_in[4];
  const float* conv5_w = (const float*)d_in[5];
  const float* conv5_b = (const float*)d_in[6];
  const float* qkv_w   = (const float*)d_in[7];
  const float* scale   = (const float*)d_in[8];
  const float* g1_w    = (const float*)d_in[9];
  const float* g1_b    = (const float*)d_in[10];
  const float* g2_w    = (const float*)d_in[11];
  const float* g2_b    = (const float*)d_in[12];
  const float* proj_w  = (const float*)d_in[13];
  const float* proj_b  = (const float*)d_in[14];
  const float* ln2_w   = (const float*)d_in[15];
  const float* ln2_b   = (const float*)d_in[16];
  const float* pin_w   = (const float*)d_in[17];
  const float* dw_w    = (const float*)d_in[18];
  const float* pout_w  = (const float*)d_in[19];
  float* out = (float*)d_out;
  char* wsb  = (char*)d_ws;

  const size_t MB = 1024*1024;
  bf* y    = (bf*)(wsb +   0*MB);
  bf* conv = (bf*)(wsb +  32*MB);
  bf* qkv  = (bf*)(wsb +  64*MB);
  bf* attnf= (bf*)(wsb +   0*MB);
  bf* xnew = (bf*)(wsb +  64*MB);
  bf* y2   = (bf*)(wsb +  96*MB);
  bf* p    = (bf*)(wsb +   0*MB);
  bf* m    = (bf*)(wsb +  96*MB);
  u16* Wqkv  = (u16*)(wsb + 160*MB);
  u16* Wproj = Wqkv + 196608;
  u16* Wpin  = Wproj + 65536;
  u16* Wpout = Wpin + 131072;
  float* gp     = (float*)(Wpout + 65536);
  float* cwaw   = gp + 1024;
  float* lscale = cwaw + 16;

  cvt_kernel<<<768,256,0,stream>>>(qkv_w,  Wqkv, 196608);
  cvt_kernel<<<256,256,0,stream>>>(proj_w, Wproj, 65536);
  cvt_kernel<<<512,256,0,stream>>>(pin_w,  Wpin, 131072);
  cvt_kernel<<<256,256,0,stream>>>(pout_w, Wpout, 65536);

  ln_kernel<float><<<256,256,0,stream>>>(x, ln1_w, ln1_b, y);
  gp_kernel<<<1024,256,0,stream>>>(y, gp);
  gate_kernel<<<1,256,0,stream>>>(gp, g1_w, g1_b, g2_w, g2_b, cwaw);
  dwconv_kernel<<<8192,256,0,stream>>>(y, conv3_w, conv3_b, conv5_w, conv5_b, conv);
  mfma_gemm<float,bf><<<dim3(512,6),256,0,stream>>>(Wqkv, y, nullptr,
                                        (const float*)nullptr, qkv, 768);
  norm_kernel<<<1024,256,0,stream>>>(qkv, scale, lscale);
  attn_mfma<0,0><<<1024,256,0,stream>>>(qkv, lscale, attnf, nullptr, nullptr);
  attn_mfma<1,1><<<1024,256,0,stream>>>(qkv, lscale, attnf, conv, cwaw);
  mfma_gemm<float,bf><<<dim3(512,2),256,0,stream>>>(Wproj, attnf, proj_b, x, xnew, 256);
  ln_kernel<bf><<<256,256,0,stream>>>(xnew, ln2_w, ln2_b, y2);
  mfma_gemm<float,bf><<<dim3(512,4),256,0,stream>>>(Wpin, y2, nullptr,
                                        (const float*)nullptr, p, 512);
  dwconv2_glu_kernel<<<8192,256,0,stream>>>(p, dw_w, m);
  mfma_gemm<bf,float><<<dim3(512,2),256,0,stream>>>(Wpout, m, nullptr, xnew, out, 256);
}

// Round 7
// 484.377 us; speedup vs baseline: 3.3110x; 1.1793x over previous
//
#include <hip/hip_runtime.h>
#include <hip/hip_bf16.h>
#include <math.h>

#define DIMC 256
#define NB   4
#define HH   128
#define WW   128
#define HWs  16384
#define HID  256
#define C2   512
#define EPSf 1e-5f

typedef __hip_bfloat16 bf;
typedef unsigned short u16;
typedef unsigned int   u32;
typedef float f32x4  __attribute__((ext_vector_type(4)));
typedef u32   u32x4  __attribute__((ext_vector_type(4)));
typedef short bf16x8 __attribute__((ext_vector_type(8)));

__device__ __forceinline__ float b2f(bf v){ return __bfloat162float(v); }
__device__ __forceinline__ bf    f2b(float v){ return __float2bfloat16(v); }
__device__ __forceinline__ float ldf(const float* p){ return *p; }
__device__ __forceinline__ float ldf(const bf* p){ return __bfloat162float(*p); }
__device__ __forceinline__ void  sto(float* p, float v){ *p = v; }
__device__ __forceinline__ void  sto(bf* p, float v){ *p = f2b(v); }
__device__ __forceinline__ void unpack2(u32 u, float& a, float& b){
  union{u32 x; float f;} lo, hi;
  lo.x = u << 16; hi.x = u & 0xffff0000u;
  a = lo.f; b = hi.f;
}
__device__ __forceinline__ u32 pack2(float a, float b){
  bf h0 = f2b(a), h1 = f2b(b);
  return (u32)*(u16*)&h0 | ((u32)*(u16*)&h1 << 16);
}
__device__ __forceinline__ void unp4(uint2 u, float* d){
  unpack2(u.x, d[0], d[1]); unpack2(u.y, d[2], d[3]);
}

__device__ __forceinline__ float gelu_exact(float v){
  return 0.5f*v*(1.0f + erff(v*0.70710678118654752f));
}

// ---------------- weight fp32 -> bf16 convert ----------------
__global__ __launch_bounds__(256) void cvt_kernel(const float* __restrict__ s,
    u16* __restrict__ d, int n){
  int i = blockIdx.x*256 + threadIdx.x;
  if (i < n){ bf h = f2b(s[i]); d[i] = *(u16*)&h; }
}

// ---------------- LayerNorm over channel dim (per pixel), bf16 out ----------------
template<typename TI>
__global__ __launch_bounds__(256) void ln_kernel(const TI* __restrict__ x,
    const float* __restrict__ w, const float* __restrict__ bb, bf* __restrict__ y){
  int p = blockIdx.x*256 + threadIdx.x;
  int b  = p >> 14;
  int sp = p & (HWs-1);
  const TI* xb = x + (size_t)b*DIMC*HWs + sp;
  float s = 0.f, s2 = 0.f;
  for(int c=0;c<DIMC;c++){ float v = ldf(xb + (size_t)c*HWs); s += v; s2 += v*v; }
  float mu   = s * (1.0f/DIMC);
  float var  = s2 * (1.0f/DIMC) - mu*mu;
  float rinv = rsqrtf(var + EPSf);
  bf* yb = y + (size_t)b*DIMC*HWs + sp;
  for(int c=0;c<DIMC;c++){
    float v = ldf(xb + (size_t)c*HWs);
    yb[(size_t)c*HWs] = f2b((v - mu)*rinv*w[c] + bb[c]);
  }
}

// ---------------- global average pool per (b,c) ----------------
__global__ __launch_bounds__(256) void gp_kernel(const bf* __restrict__ y, float* __restrict__ gp){
  int bc = blockIdx.x;
  const bf* pl = y + (size_t)bc*HWs;
  float s = 0.f;
  for(int i=threadIdx.x;i<HWs;i+=256) s += b2f(pl[i]);
  __shared__ float red[256];
  red[threadIdx.x] = s; __syncthreads();
  for(int o=128;o>0;o>>=1){
    if(threadIdx.x<o) red[threadIdx.x] += red[threadIdx.x+o];
    __syncthreads();
  }
  if(threadIdx.x==0) gp[bc] = red[0]*(1.0f/HWs);
}

// ---------------- gating MLP (tiny) ----------------
__global__ __launch_bounds__(256) void gate_kernel(const float* __restrict__ gp,
    const float* __restrict__ g1w, const float* __restrict__ g1b,
    const float* __restrict__ g2w, const float* __restrict__ g2b,
    float* __restrict__ cwaw){
  __shared__ float h[NB][64];
  __shared__ float zz[NB][2];
  int t = threadIdx.x;
  int b = t >> 6, j = t & 63;
  const float* gpb = gp + b*DIMC;
  const float* wr  = g1w + j*DIMC;
  float s = g1b[j];
  for(int c=0;c<DIMC;c++) s += gpb[c]*wr[c];
  h[b][j] = fmaxf(s, 0.f);
  __syncthreads();
  if (t < 8){
    int b2 = t >> 1, o = t & 1;
    float z = g2b[o];
    const float* w2 = g2w + o*64;
    for(int q=0;q<64;q++) z += w2[q]*h[b2][q];
    zz[b2][o] = z;
  }
  __syncthreads();
  if (t < 4){
    float z0 = zz[t][0], z1 = zz[t][1];
    float mm = fmaxf(z0,z1);
    float e0 = __expf(z0-mm), e1 = __expf(z1-mm);
    float inv = 1.0f/(e0+e1);
    cwaw[2*t]   = e0*inv;
    cwaw[2*t+1] = e1*inv;
  }
}

// ---------------- depthwise conv 3x3 + 5x5, block-uniform channel ----------------
// block = (b, c, 16-row strip); thread = (row, 8-wide x strip); weights scalar
__global__ __launch_bounds__(256) void dwconv_kernel(const bf* __restrict__ y,
    const float* __restrict__ w3, const float* __restrict__ b3,
    const float* __restrict__ w5, const float* __restrict__ b5,
    bf* __restrict__ out){
  int bi = blockIdx.x;                 // 4*256*8
  int strip = bi & 7;
  int c  = (bi >> 3) & 255;
  int b  = bi >> 11;
  int t = threadIdx.x;
  int sx = t & 15, ry = t >> 4;
  int hy = strip*16 + ry;
  int x0 = sx << 3;
  const u16* pl = (const u16*)y + ((size_t)(b*DIMC + c))*HWs;

  float kc[25];
  #pragma unroll
  for(int i=0;i<25;i++) kc[i] = w5[c*25+i];
  #pragma unroll
  for(int di=0;di<3;di++)
    #pragma unroll
    for(int dj=0;dj<3;dj++)
      kc[(di+1)*5 + (dj+1)] += w3[c*9 + di*3 + dj];
  float bia = b3[c] + b5[c];

  float acc[8];
  #pragma unroll
  for(int j=0;j<8;j++) acc[j] = bia;

  #pragma unroll
  for(int di=-2; di<=2; di++){
    int yy = hy + di;
    float row[16];
    if ((unsigned)yy < 128u){
      const u16* rp = pl + yy*WW;
      uint2 z; z.x = 0u; z.y = 0u;
      uint2 c0 = (x0 > 0)   ? *(const uint2*)(rp + x0 - 4) : z;
      uint2 c1 = *(const uint2*)(rp + x0);
      uint2 c2 = *(const uint2*)(rp + x0 + 4);
      uint2 c3 = (x0 < 120) ? *(const uint2*)(rp + x0 + 8) : z;
      unp4(c0, row); unp4(c1, row+4); unp4(c2, row+8); unp4(c3, row+12);
    } else {
      #pragma unroll
      for(int j=0;j<16;j++) row[j] = 0.f;
    }
    #pragma unroll
    for(int dj=-2; dj<=2; dj++){
      float w = kc[(di+2)*5 + (dj+2)];
      #pragma unroll
      for(int j=0;j<8;j++) acc[j] += row[4+j+dj]*w;
    }
  }
  u32x4 res;
  #pragma unroll
  for(int q=0;q<4;q++) ((u32*)&res)[q] = pack2(acc[2*q], acc[2*q+1]);
  *(u32x4*)((u16*)out + ((size_t)(b*DIMC + c))*HWs + hy*WW + x0) = res;
}

// ---------------- grouped conv (2-2 per group, 3x3) + GLU, o-pair per thread ----------------
// block = (b, o-pair, 16-row strip); weights scalar; input planes shared by o/o+1
__global__ __launch_bounds__(256) void dwconv2_glu_kernel(const bf* __restrict__ p,
    const float* __restrict__ w, bf* __restrict__ m){
  int bi = blockIdx.x;                 // 4*128*8
  int strip = bi & 7;
  int op = (bi >> 3) & 127;
  int b  = bi >> 10;
  int o0 = op*2, o1 = o0+1;
  int t = threadIdx.x;
  int sx = t & 15, ry = t >> 4;
  int hy = strip*16 + ry;
  int x0 = sx << 3;
  const u16* p0 = (const u16*)p + ((size_t)b*C2 + o0)*HWs;
  const u16* p1 = p0 + HWs;
  const u16* p2 = p0 + (size_t)256*HWs;
  const u16* p3 = p2 + HWs;

  float KA0[9], KA1[9], KA2[9], KA3[9];
  float KB0[9], KB1[9], KB2[9], KB3[9];
  #pragma unroll
  for(int i=0;i<9;i++){
    KA0[i] = w[o0*18 + i];        KA1[i] = w[o0*18 + 9 + i];
    KA2[i] = w[(o0+256)*18 + i];  KA3[i] = w[(o0+256)*18 + 9 + i];
    KB0[i] = w[o1*18 + i];        KB1[i] = w[o1*18 + 9 + i];
    KB2[i] = w[(o1+256)*18 + i];  KB3[i] = w[(o1+256)*18 + 9 + i];
  }

  float a1A[8] = {}, a2A[8] = {}, a1B[8] = {}, a2B[8] = {};
  #pragma unroll
  for(int di=-1; di<=1; di++){
    int yy = hy + di;
    if ((unsigned)yy >= 128u) continue;
    int roff = yy*WW;
    float r0[16], r1[16], r2[16], r3[16];
    uint2 z; z.x = 0u; z.y = 0u;
    bool lo = (x0 > 0), hi = (x0 < 120);
    {
      const u16* rp = p0 + roff;
      uint2 c0 = lo ? *(const uint2*)(rp + x0 - 4) : z;
      uint2 c1 = *(const uint2*)(rp + x0);
      uint2 c2 = *(const uint2*)(rp + x0 + 4);
      uint2 c3 = hi ? *(const uint2*)(rp + x0 + 8) : z;
      unp4(c0, r0); unp4(c1, r0+4); unp4(c2, r0+8); unp4(c3, r0+12);
    }
    {
      const u16* rp = p1 + roff;
      uint2 c0 = lo ? *(const uint2*)(rp + x0 - 4) : z;
      uint2 c1 = *(const uint2*)(rp + x0);
      uint2 c2 = *(const uint2*)(rp + x0 + 4);
      uint2 c3 = hi ? *(const uint2*)(rp + x0 + 8) : z;
      unp4(c0, r1); unp4(c1, r1+4); unp4(c2, r1+8); unp4(c3, r1+12);
    }
    {
      const u16* rp = p2 + roff;
      uint2 c0 = lo ? *(const uint2*)(rp + x0 - 4) : z;
      uint2 c1 = *(const uint2*)(rp + x0);
      uint2 c2 = *(const uint2*)(rp + x0 + 4);
      uint2 c3 = hi ? *(const uint2*)(rp + x0 + 8) : z;
      unp4(c0, r2); unp4(c1, r2+4); unp4(c2, r2+8); unp4(c3, r2+12);
    }
    {
      const u16* rp = p3 + roff;
      uint2 c0 = lo ? *(const uint2*)(rp + x0 - 4) : z;
      uint2 c1 = *(const uint2*)(rp + x0);
      uint2 c2 = *(const uint2*)(rp + x0 + 4);
      uint2 c3 = hi ? *(const uint2*)(rp + x0 + 8) : z;
      unp4(c0, r3); unp4(c1, r3+4); unp4(c2, r3+8); unp4(c3, r3+12);
    }
    #pragma unroll
    for(int dj=-1; dj<=1; dj++){
      int ki = (di+1)*3 + (dj+1);
      #pragma unroll
      for(int j=0;j<8;j++){
        int ii = 4+j+dj;
        a1A[j] += r0[ii]*KA0[ki] + r1[ii]*KA1[ki];
        a2A[j] += r2[ii]*KA2[ki] + r3[ii]*KA3[ki];
        a1B[j] += r0[ii]*KB0[ki] + r1[ii]*KB1[ki];
        a2B[j] += r2[ii]*KB2[ki] + r3[ii]*KB3[ki];
      }
    }
  }
  size_t obase = ((size_t)(b*DIMC + o0))*HWs + hy*WW + x0;
  u32x4 resA, resB;
  #pragma unroll
  for(int q=0;q<4;q++){
    ((u32*)&resA)[q] = pack2(gelu_exact(a1A[2*q])*a2A[2*q],
                             gelu_exact(a1A[2*q+1])*a2A[2*q+1]);
    ((u32*)&resB)[q] = pack2(gelu_exact(a1B[2*q])*a2B[2*q],
                             gelu_exact(a1B[2*q+1])*a2B[2*q+1]);
  }
  *(u32x4*)((u16*)m + obase) = resA;
  *(u32x4*)((u16*)m + obase + HWs) = resB;
}

// ---------------- bf16 MFMA GEMM (unchanged, passed R5/R6) ----------------
template<typename TRES, typename TOUT>
__global__ __launch_bounds__(256, 2) void mfma_gemm(
    const u16* __restrict__ Wb, const bf* __restrict__ act,
    const float* __restrict__ bias, const TRES* __restrict__ resid,
    TOUT* __restrict__ out, int Oc)
{
  __shared__ u16 Bs[2][4096];
  int t  = threadIdx.x;
  int n0 = blockIdx.x * 128;
  int o0 = blockIdx.y * 128;
  int b  = n0 >> 14;
  int sp = n0 & (HWs-1);
  const u16* actu = (const u16*)act + (size_t)b*256*HWs + sp;

  int kp = t & 15;
  int ns = (t >> 4) << 3;
  int lane = t & 63;
  int wv = t >> 6;
  int wr = (wv >> 1) << 6;
  int wc = (wv & 1) << 6;
  int fr = lane & 15;
  int kg = lane >> 4;

  f32x4 acc[4][4] = {};

  auto stage = [&](int ks, int buf){
    const u16* r0 = actu + (size_t)(ks*32 + 2*kp)*HWs + ns;
    u32x4 u = *(const u32x4*)r0;
    u32x4 v = *(const u32x4*)(r0 + HWs);
    u32 w0=(u.x&0xffffu)|(v.x<<16), w1=(u.x>>16)|(v.x&0xffff0000u);
    u32 w2=(u.y&0xffffu)|(v.y<<16), w3=(u.y>>16)|(v.y&0xffff0000u);
    u32 w4=(u.z&0xffffu)|(v.z<<16), w5=(u.z>>16)|(v.z&0xffff0000u);
    u32 w6=(u.w&0xffffu)|(v.w<<16), w7=(u.w>>16)|(v.w&0xffff0000u);
    u16* bp = Bs[buf];
    int c0 = kp*2;
    *(u32*)&bp[(ns+0)*32+c0]=w0; *(u32*)&bp[(ns+1)*32+c0]=w1;
    *(u32*)&bp[(ns+2)*32+c0]=w2; *(u32*)&bp[(ns+3)*32+c0]=w3;
    *(u32*)&bp[(ns+4)*32+c0]=w4; *(u32*)&bp[(ns+5)*32+c0]=w5;
    *(u32*)&bp[(ns+6)*32+c0]=w6; *(u32*)&bp[(ns+7)*32+c0]=w7;
  };

  stage(0, 0);
  #pragma unroll
  for(int ks=0; ks<8; ++ks){
    int cur = ks & 1;
    __syncthreads();
    if (ks < 7) stage(ks+1, cur^1);
    bf16x8 af[4], bfr[4];
    #pragma unroll
    for(int i=0;i<4;i++)
      af[i] = *(const bf16x8*)(Wb + (size_t)(o0+wr+i*16+fr)*256 + ks*32 + kg*8);
    #pragma unroll
    for(int j=0;j<4;j++)
      bfr[j] = *(const bf16x8*)&Bs[cur][(wc + j*16 + fr)*32 + kg*8];
    #pragma unroll
    for(int i=0;i<4;i++)
      #pragma unroll
      for(int j=0;j<4;j++)
        acc[i][j] = __builtin_amdgcn_mfma_f32_16x16x32_bf16(af[i], bfr[j], acc[i][j], 0, 0, 0);
  }

  #pragma unroll
  for(int i=0;i<4;i++){
    #pragma unroll
    for(int reg=0;reg<4;reg++){
      int o = o0 + wr + i*16 + kg*4 + reg;
      size_t rowoff = ((size_t)b*Oc + o)*HWs + sp + wc + fr;
      float bia = bias ? bias[o] : 0.f;
      #pragma unroll
      for(int j=0;j<4;j++){
        float val = acc[i][j][reg] + bia;
        size_t pidx = rowoff + (size_t)(j*16);
        if (resid) val += ldf(resid + pidx);
        sto(out + pidx, val);
      }
    }
  }
}

// ---------------- per-slice logit scale ----------------
__global__ __launch_bounds__(256) void norm_kernel(const bf* __restrict__ qkv,
    const float* __restrict__ scale, float* __restrict__ lscale){
  int s = blockIdx.x;
  int b = s >> 8, ch = s & 255;
  const bf* qp = qkv + ((size_t)b*768 + ch)*HWs;
  const bf* kp = qp + (size_t)256*HWs;
  float sq=0.f, sk=0.f;
  for(int i=threadIdx.x;i<HWs;i+=256){
    float a = b2f(qp[i]); sq += a*a;
    float c = b2f(kp[i]); sk += c*c;
  }
  __shared__ float r1[256], r2[256];
  r1[threadIdx.x]=sq; r2[threadIdx.x]=sk;
  __syncthreads();
  for(int o=128;o>0;o>>=1){
    if(threadIdx.x<o){ r1[threadIdx.x]+=r1[threadIdx.x+o]; r2[threadIdx.x]+=r2[threadIdx.x+o]; }
    __syncthreads();
  }
  if(threadIdx.x==0){
    float nq = fmaxf(sqrtf(r1[0]), 1e-12f);
    float nk = fmaxf(sqrtf(r2[0]), 1e-12f);
    lscale[s] = scale[ch & 15] / (nq*nk);
  }
}

// byte offset into a [128 rows][128 bf16] LDS plane, 16B-chunk XOR swizzled
#define SWB(r,c2) ((r)*256 + ((c2) ^ (((r)&7)<<4)))

// ---------------- MFMA axial attention, BOTH directions in one dispatch ----------------
// dir0 O accumulates into oacc; dir1's O-MFMA continues accumulation (C-in = C-out).
// Final: out = cw*conv + aw*(O0+O1), written once.
__global__ __launch_bounds__(256, 2) void attn_mfma(const bf* __restrict__ qkv,
    const float* __restrict__ lscale, bf* __restrict__ outp,
    const bf* __restrict__ conv, const float* __restrict__ cwaw){
  __shared__ u16 LB0[16384];
  __shared__ u16 LB1[16384];
  int s  = blockIdx.x;
  int b  = s >> 8;
  int ch = s & 255;
  const u16* qp = (const u16*)qkv + ((size_t)b*768 + ch)*HWs;
  const u16* kp = qp + (size_t)256*HWs;
  const u16* vp = qp + (size_t)512*HWs;
  int t = threadIdx.x;
  float ls = lscale[s];

  int lane = t & 63, wvi = t >> 6;
  int fr = lane & 15, kg = lane >> 4;
  int nb = wvi << 5;
  int rr = t >> 1, hb = (t & 1) << 7;

  auto stage_nat = [&](const u16* src, u16* dst){
    #pragma unroll
    for(int i=0;i<8;i++){
      int c2 = hb + i*16;
      u32x4 v = *(const u32x4*)((const char*)src + rr*256 + c2);
      *(u32x4*)((char*)dst + SWB(rr, c2)) = v;
    }
  };
  auto stage_tr = [&](const u16* src, u16* dst){
    int kp2 = (t & 15)*2, cs = (t >> 4) << 3;
    #pragma unroll
    for(int base=0;base<128;base+=32){
      int sr = base + kp2;
      u32x4 u = *(const u32x4*)(src + sr*128 + cs);
      u32x4 v = *(const u32x4*)(src + (sr+1)*128 + cs);
      #pragma unroll
      for(int j=0;j<8;j++){
        u32 uw = ((const u32*)&u)[j>>1];
        u32 vw = ((const u32*)&v)[j>>1];
        u32 wv = (j&1) ? ((uw>>16) | (vw & 0xffff0000u))
                       : ((uw & 0xffffu) | (vw<<16));
        *(u32*)((char*)dst + SWB(cs+j, sr*2)) = wv;
      }
    }
  };

  f32x4 acc[8][2];     // S fragments / P
  f32x4 oacc[8][2];    // O0+O1 running accumulator
  const f32x4 vzero = {};

  auto mmloop = [&](const u16* afsrc, const u16* bfsrc, f32x4 (&A)[8][2]){
    #pragma unroll
    for(int kk=0;kk<128;kk+=32){
      int kb2 = kk*2 + kg*16;
      bf16x8 b0 = *(const bf16x8*)((const char*)bfsrc + SWB(nb+fr,    kb2));
      bf16x8 b1 = *(const bf16x8*)((const char*)bfsrc + SWB(nb+16+fr, kb2));
      #pragma unroll
      for(int mt=0;mt<8;mt++){
        bf16x8 a0 = *(const bf16x8*)((const char*)afsrc + SWB(mt*16+fr, kb2));
        A[mt][0] = __builtin_amdgcn_mfma_f32_16x16x32_bf16(a0, b0, A[mt][0], 0, 0, 0);
        A[mt][1] = __builtin_amdgcn_mfma_f32_16x16x32_bf16(a0, b1, A[mt][1], 0, 0, 0);
      }
    }
  };

  auto writeCT = [&](u16* dst, f32x4 (&A)[8][2]){
    #pragma unroll
    for(int nt=0;nt<2;nt++){
      int n = nb + nt*16 + fr;
      #pragma unroll
      for(int mt=0;mt<8;mt++){
        #pragma unroll
        for(int pr=0;pr<2;pr++){
          u32 wv = pack2(A[mt][nt][pr*2], A[mt][nt][pr*2+1]);
          int z2 = (mt*16 + kg*4 + pr*2)*2;
          *(u32*)((char*)dst + SWB(n, z2)) = wv;
        }
      }
    }
  };

  auto softmax = [&](){
    #pragma unroll
    for(int nt=0;nt<2;nt++){
      float mx = -1e30f;
      #pragma unroll
      for(int mt=0;mt<8;mt++)
        #pragma unroll
        for(int rg=0;rg<4;rg++){
          acc[mt][nt][rg] *= ls;
          mx = fmaxf(mx, acc[mt][nt][rg]);
        }
      mx = fmaxf(mx, __shfl_xor(mx,16));
      mx = fmaxf(mx, __shfl_xor(mx,32));
      float sm = 0.f;
      #pragma unroll
      for(int mt=0;mt<8;mt++)
        #pragma unroll
        for(int rg=0;rg<4;rg++){
          float e = __expf(acc[mt][nt][rg]-mx);
          acc[mt][nt][rg] = e; sm += e;
        }
      sm += __shfl_xor(sm,16);
      sm += __shfl_xor(sm,32);
      float inv = 1.0f/sm;
      #pragma unroll
      for(int mt=0;mt<8;mt++)
        #pragma unroll
        for(int rg=0;rg<4;rg++)
          acc[mt][nt][rg] *= inv;
    }
  };

  // ---- dir 0 ----
  stage_nat(kp, LB0); stage_nat(qp, LB1);
  __syncthreads();
  #pragma unroll
  for(int mt=0;mt<8;mt++){ acc[mt][0]=vzero; acc[mt][1]=vzero; }
  mmloop(LB0, LB1, acc);
  softmax();
  __syncthreads();
  writeCT(LB0, acc);                  // P
  stage_tr(vp, LB1);                  // V^T
  __syncthreads();
  #pragma unroll
  for(int mt=0;mt<8;mt++){ oacc[mt][0]=vzero; oacc[mt][1]=vzero; }
  mmloop(LB1, LB0, oacc);             // O0
  __syncthreads();

  // ---- dir 1 ----
  stage_tr(kp, LB0); stage_tr(qp, LB1);
  __syncthreads();
  #pragma unroll
  for(int mt=0;mt<8;mt++){ acc[mt][0]=vzero; acc[mt][1]=vzero; }
  mmloop(LB0, LB1, acc);
  softmax();
  __syncthreads();
  writeCT(LB0, acc);                  // P
  stage_nat(vp, LB1);                 // V
  __syncthreads();
  mmloop(LB0, LB1, oacc);             // O0 + O1 (accumulate)
  __syncthreads();

  writeCT(LB0, oacc);                 // spatial [h][w]
  __syncthreads();

  // copy-out with conv mix
  float cw = cwaw[2*b], aw = cwaw[2*b+1];
  const u16* cp = (const u16*)conv + ((size_t)b*DIMC + ch)*HWs;
  bf* op = outp + ((size_t)b*DIMC + ch)*HWs;
  #pragma unroll
  for(int i=0;i<8;i++){
    int c2 = hb + i*16;
    u32x4 ov = *(const u32x4*)((char*)LB0 + SWB(rr, c2));
    u32x4 cv = *(const u32x4*)(cp + rr*128 + c2/2);
    u32x4 res;
    #pragma unroll
    for(int q=0;q<4;q++){
      float o0,o1,c0,c1;
      unpack2(((u32*)&ov)[q], o0, o1);
      unpack2(((u32*)&cv)[q], c0, c1);
      ((u32*)&res)[q] = pack2(cw*c0 + aw*o0, cw*c1 + aw*o1);
    }
    *(u32x4*)((u16*)op + rr*128 + c2/2) = res;
  }
}

// ---------------- launch ----------------
extern "C" void kernel_launch(void* const* d_in, const int* in_sizes, int n_in,
                              void* d_out, int out_size, void* d_ws, size_t ws_size,
                              hipStream_t stream){
  (void)in_sizes; (void)n_in; (void)out_size; (void)ws_size;
  const float* x       = (const float*)d_in[0];
  const float* ln1_w   = (const float*)d_in[1];
  const float* ln1_b   = (const float*)d_in[2];
  const float* conv3_w = (const float*)d_in[3];
  const float* conv3_b = (const float*)d_in[4];
  const float* conv5_w = (const float*)d_in[5];
  const float* conv5_b = (const float*)d_in[6];
  const float* qkv_w   = (const float*)d_in[7];
  const float* scale   = (const float*)d_in[8];
  const float* g1_w    = (const float*)d_in[9];
  const float* g1_b    = (const float*)d_in[10];
  const float* g2_w    = (const float*)d_in[11];
  const float* g2_b    = (const float*)d_in[12];
  const float* proj_w  = (const float*)d_in[13];
  const float* proj_b  = (const float*)d_in[14];
  const float* ln2_w   = (const float*)d_in[15];
  const float* ln2_b   = (const float*)d_in[16];
  const float* pin_w   = (const float*)d_in[17];
  const float* dw_w    = (const float*)d_in[18];
  const float* pout_w  = (const float*)d_in[19];
  float* out = (float*)d_out;
  char* wsb  = (char*)d_ws;

  const size_t MB = 1024*1024;
  bf* y    = (bf*)(wsb +   0*MB);
  bf* conv = (bf*)(wsb +  32*MB);
  bf* qkv  = (bf*)(wsb +  64*MB);
  bf* attnf= (bf*)(wsb +   0*MB);
  bf* xnew = (bf*)(wsb +  64*MB);
  bf* y2   = (bf*)(wsb +  96*MB);
  bf* p    = (bf*)(wsb +   0*MB);
  bf* m    = (bf*)(wsb +  96*MB);
  u16* Wqkv  = (u16*)(wsb + 160*MB);
  u16* Wproj = Wqkv + 196608;
  u16* Wpin  = Wproj + 65536;
  u16* Wpout = Wpin + 131072;
  float* gp     = (float*)(Wpout + 65536);
  float* cwaw   = gp + 1024;
  float* lscale = cwaw + 16;

  cvt_kernel<<<768,256,0,stream>>>(qkv_w,  Wqkv, 196608);
  cvt_kernel<<<256,256,0,stream>>>(proj_w, Wproj, 65536);
  cvt_kernel<<<512,256,0,stream>>>(pin_w,  Wpin, 131072);
  cvt_kernel<<<256,256,0,stream>>>(pout_w, Wpout, 65536);

  ln_kernel<float><<<256,256,0,stream>>>(x, ln1_w, ln1_b, y);
  gp_kernel<<<1024,256,0,stream>>>(y, gp);
  gate_kernel<<<1,256,0,stream>>>(gp, g1_w, g1_b, g2_w, g2_b, cwaw);
  dwconv_kernel<<<8192,256,0,stream>>>(y, conv3_w, conv3_b, conv5_w, conv5_b, conv);
  mfma_gemm<float,bf><<<dim3(512,6),256,0,stream>>>(Wqkv, y, nullptr,
                                        (const float*)nullptr, qkv, 768);
  norm_kernel<<<1024,256,0,stream>>>(qkv, scale, lscale);
  attn_mfma<<<1024,256,0,stream>>>(qkv, lscale, attnf, conv, cwaw);
  mfma_gemm<float,bf><<<dim3(512,2),256,0,stream>>>(Wproj, attnf, proj_b, x, xnew, 256);
  ln_kernel<bf><<<256,256,0,stream>>>(xnew, ln2_w, ln2_b, y2);
  mfma_gemm<float,bf><<<dim3(512,4),256,0,stream>>>(Wpin, y2, nullptr,
                                        (const float*)nullptr, p, 512);
  dwconv2_glu_kernel<<<4096,256,0,stream>>>(p, dw_w, m);
  mfma_gemm<bf,float><<<dim3(512,2),256,0,stream>>>(Wpout, m, nullptr, xnew, out, 256);
}